// Round 1
// baseline (817.745 us; speedup 1.0000x reference)
//
#include <hip/hip_runtime.h>

#define D 64

// ---------------- CSR build ----------------

__global__ void k_hist(const int* __restrict__ col, int E, int* __restrict__ count) {
    int e = blockIdx.x * 256 + threadIdx.x;
    if (e < E) atomicAdd(&count[col[e]], 1);
}

// tile = 1024 elements per block (256 threads x 4)
__global__ void k_scan1(const int* __restrict__ count, int n, int* __restrict__ partial) {
    __shared__ int sh[256];
    int base = blockIdx.x * 1024 + threadIdx.x * 4;
    int s = 0;
#pragma unroll
    for (int i = 0; i < 4; i++) { int idx = base + i; if (idx < n) s += count[idx]; }
    sh[threadIdx.x] = s; __syncthreads();
    for (int off = 1; off < 256; off <<= 1) {
        int v = (threadIdx.x >= (unsigned)off) ? sh[threadIdx.x - off] : 0;
        __syncthreads();
        sh[threadIdx.x] += v;
        __syncthreads();
    }
    if (threadIdx.x == 255) partial[blockIdx.x] = sh[255];
}

__global__ void k_scan2(const int* __restrict__ partial, int nb, int* __restrict__ basearr) {
    __shared__ int sh[256];
    int v = ((int)threadIdx.x < nb) ? partial[threadIdx.x] : 0;
    sh[threadIdx.x] = v; __syncthreads();
    for (int off = 1; off < 256; off <<= 1) {
        int u = (threadIdx.x >= (unsigned)off) ? sh[threadIdx.x - off] : 0;
        __syncthreads();
        sh[threadIdx.x] += u;
        __syncthreads();
    }
    if ((int)threadIdx.x < nb) basearr[threadIdx.x] = sh[threadIdx.x] - v;  // exclusive
}

__global__ void k_scan3(const int* __restrict__ count, int n, const int* __restrict__ basearr,
                        int* __restrict__ rowptr) {
    __shared__ int sh[256];
    int base = blockIdx.x * 1024 + threadIdx.x * 4;
    int c[4]; int s = 0;
#pragma unroll
    for (int i = 0; i < 4; i++) { int idx = base + i; c[i] = (idx < n) ? count[idx] : 0; s += c[i]; }
    sh[threadIdx.x] = s; __syncthreads();
    for (int off = 1; off < 256; off <<= 1) {
        int v = (threadIdx.x >= (unsigned)off) ? sh[threadIdx.x - off] : 0;
        __syncthreads();
        sh[threadIdx.x] += v;
        __syncthreads();
    }
    int run = basearr[blockIdx.x] + (sh[threadIdx.x] - s);  // exclusive prefix for this thread
#pragma unroll
    for (int i = 0; i < 4; i++) {
        int idx = base + i;
        if (idx < n) { rowptr[idx] = run; run += c[i]; }
    }
}

__global__ void k_dinv_cursor(const int* __restrict__ count, const int* __restrict__ rowptr,
                              float* __restrict__ dinv, int* __restrict__ cursor, int N) {
    int i = blockIdx.x * 256 + threadIdx.x;
    if (i < N) {
        dinv[i] = rsqrtf((float)(count[i] + 1));  // +1 self loop; always > 0
        cursor[i] = rowptr[i];
    }
}

__global__ void k_scatter(const int* __restrict__ row, const int* __restrict__ col, int E,
                          int* __restrict__ cursor, int* __restrict__ srcs) {
    int e = blockIdx.x * 256 + threadIdx.x;
    if (e < E) {
        int c = col[e];
        int p = atomicAdd(&cursor[c], 1);
        srcs[p] = row[e];
    }
}

// ---------------- dense: h[n][c] = dinv[n] * sum_k x[n][k] * W[k][c] ----------------
// x = concat(xu [U rows], xj [N-U rows]); pass (x1, x1, N) for a single source.

__global__ __launch_bounds__(256) void k_gemm(const float* __restrict__ xu, const float* __restrict__ xj,
                                              int U, int N, const float* __restrict__ W,
                                              const float* __restrict__ dinv, float* __restrict__ h) {
    __shared__ float Ws[64 * 64];
    __shared__ float Xs[64 * 68];  // stride 68 to break bank aliasing
    int tid = threadIdx.x;
#pragma unroll
    for (int i = 0; i < 16; i++) Ws[tid + i * 256] = W[tid + i * 256];
    int n0 = blockIdx.x * 64;
#pragma unroll
    for (int i = 0; i < 4; i++) {
        int e4 = tid + i * 256;          // float4 id within 64 nodes x 16 float4s
        int nl = e4 >> 4, k4 = e4 & 15;
        int nn = n0 + nl;
        float4 v = make_float4(0.f, 0.f, 0.f, 0.f);
        if (nn < N) {
            const float* src = (nn < U) ? (xu + (size_t)nn * D) : (xj + (size_t)(nn - U) * D);
            v = *(const float4*)(src + k4 * 4);
        }
        *(float4*)(&Xs[nl * 68 + k4 * 4]) = v;
    }
    __syncthreads();
    int tx = tid & 15, ty = tid >> 4;  // thread computes 4 nodes x 4 cols
    float acc[4][4];
#pragma unroll
    for (int r = 0; r < 4; r++)
#pragma unroll
        for (int c = 0; c < 4; c++) acc[r][c] = 0.f;
#pragma unroll 16
    for (int k = 0; k < 64; k++) {
        float xv[4], wv[4];
#pragma unroll
        for (int r = 0; r < 4; r++) xv[r] = Xs[(ty * 4 + r) * 68 + k];
#pragma unroll
        for (int c = 0; c < 4; c++) wv[c] = Ws[k * 64 + tx * 4 + c];
#pragma unroll
        for (int r = 0; r < 4; r++)
#pragma unroll
            for (int c = 0; c < 4; c++) acc[r][c] += xv[r] * wv[c];
    }
#pragma unroll
    for (int r = 0; r < 4; r++) {
        int nn = n0 + ty * 4 + r;
        if (nn < N) {
            float sc = dinv[nn];
            float4 o = make_float4(acc[r][0] * sc, acc[r][1] * sc, acc[r][2] * sc, acc[r][3] * sc);
            *(float4*)(&h[(size_t)nn * D + tx * 4]) = o;
        }
    }
}

// ---------------- pull aggregation (full N): xout[c] = relu?(dinv[c]*(hs[c] + sum_src hs[s]) + b) --------

__global__ __launch_bounds__(256) void k_agg(const float* __restrict__ hs, const float* __restrict__ dinv,
                                             const int* __restrict__ rowptr, const int* __restrict__ srcs,
                                             const float* __restrict__ bias, float* __restrict__ xout,
                                             int N, int do_relu) {
    int node = blockIdx.x * 4 + (threadIdx.x >> 6);
    int lane = threadIdx.x & 63;
    if (node >= N) return;
    float acc = hs[(size_t)node * D + lane];  // self loop (hs already has dinv[node] folded)
    int e1 = rowptr[node + 1];
    for (int base0 = rowptr[node]; base0 < e1; base0 += 64) {
        int j = base0 + lane;
        int s = (j < e1) ? srcs[j] : 0;
        int cnt = min(64, e1 - base0);
        for (int i = 0; i < cnt; i++) {
            int si = __shfl(s, i, 64);
            acc += hs[(size_t)si * D + lane];
        }
    }
    acc = acc * dinv[node] + bias[lane];
    if (do_relu) acc = fmaxf(acc, 0.f);
    xout[(size_t)node * D + lane] = acc;
}

// ---------------- fused layer-2 aggregation (selected nodes only) + prediction ----------------

__global__ void k_initout(const float* __restrict__ pb, float* __restrict__ out, int B) {
    int i = blockIdx.x * 256 + threadIdx.x;
    if (i < B) out[i] = pb[0];
}

__global__ __launch_bounds__(256) void k_pred(const float* __restrict__ hs2, const float* __restrict__ dinv,
                                              const int* __restrict__ rowptr, const int* __restrict__ srcs,
                                              const float* __restrict__ b2, const float* __restrict__ pw,
                                              const int* __restrict__ uidx, const int* __restrict__ jidx,
                                              int U, int B, float* __restrict__ out) {
    int wid = blockIdx.x * 4 + (threadIdx.x >> 6);
    int lane = threadIdx.x & 63;
    if (wid >= 2 * B) return;
    int isU = (wid < B);
    int b = isU ? wid : wid - B;
    int c = isU ? uidx[b] : U + jidx[b];
    float acc = hs2[(size_t)c * D + lane];
    int e1 = rowptr[c + 1];
    for (int base0 = rowptr[c]; base0 < e1; base0 += 64) {
        int j = base0 + lane;
        int s = (j < e1) ? srcs[j] : 0;
        int cnt = min(64, e1 - base0);
        for (int i = 0; i < cnt; i++) {
            int si = __shfl(s, i, 64);
            acc += hs2[(size_t)si * D + lane];
        }
    }
    acc = acc * dinv[c] + b2[lane];
    float v = acc * pw[(isU ? 0 : 64) + lane];
#pragma unroll
    for (int off = 32; off >= 1; off >>= 1) v += __shfl_xor(v, off, 64);
    if (lane == 0) atomicAdd(&out[b], v);
}

// ---------------- host ----------------

extern "C" void kernel_launch(void* const* d_in, const int* in_sizes, int n_in,
                              void* d_out, int out_size, void* d_ws, size_t ws_size,
                              hipStream_t stream) {
    const int*   edge = (const int*)d_in[0];
    const int*   uidx = (const int*)d_in[1];
    const int*   jidx = (const int*)d_in[2];
    const float* xu   = (const float*)d_in[3];
    const float* xj   = (const float*)d_in[4];
    const float* W1   = (const float*)d_in[5];
    const float* b1   = (const float*)d_in[6];
    const float* W2   = (const float*)d_in[7];
    const float* b2   = (const float*)d_in[8];
    const float* pw   = (const float*)d_in[9];
    const float* pb   = (const float*)d_in[10];
    float* out = (float*)d_out;

    int E = in_sizes[0] / 2;
    int B = in_sizes[1];
    int U = in_sizes[3] / D;
    int J = in_sizes[4] / D;
    int N = U + J;
    const int* row = edge;       // sources
    const int* col = edge + E;   // targets

    char* p = (char*)d_ws;
    auto alloc = [&](size_t bytes) -> void* {
        void* q = (void*)p;
        p += (bytes + 255) / 256 * 256;
        return q;
    };
    int*   count   = (int*)alloc((size_t)(N + 1) * 4);
    int*   rowptr  = (int*)alloc((size_t)(N + 1) * 4);
    int*   partial = (int*)alloc(256 * 4);
    int*   basearr = (int*)alloc(256 * 4);
    float* dinv    = (float*)alloc((size_t)N * 4);
    int*   cursor  = (int*)alloc((size_t)N * 4);
    int*   srcs    = (int*)alloc((size_t)E * 4);
    float* h       = (float*)alloc((size_t)N * D * 4);  // reused for layer-2 hs
    float* x1      = (float*)alloc((size_t)N * D * 4);

    hipMemsetAsync(count, 0, (size_t)(N + 1) * 4, stream);
    k_hist<<<(E + 255) / 256, 256, 0, stream>>>(col, E, count);

    int n_scan = N + 1;
    int NB = (n_scan + 1023) / 1024;  // 196 for N=200000; must be <= 256
    k_scan1<<<NB, 256, 0, stream>>>(count, n_scan, partial);
    k_scan2<<<1, 256, 0, stream>>>(partial, NB, basearr);
    k_scan3<<<NB, 256, 0, stream>>>(count, n_scan, basearr, rowptr);
    k_dinv_cursor<<<(N + 255) / 256, 256, 0, stream>>>(count, rowptr, dinv, cursor, N);
    k_scatter<<<(E + 255) / 256, 256, 0, stream>>>(row, col, E, cursor, srcs);

    // layer 1: hs = (x @ W1) * dinv ; x1 = relu(dinv*(hs_self + sum) + b1)
    k_gemm<<<(N + 63) / 64, 256, 0, stream>>>(xu, xj, U, N, W1, dinv, h);
    k_agg<<<(N + 3) / 4, 256, 0, stream>>>(h, dinv, rowptr, srcs, b1, x1, N, 1);

    // layer 2: hs2 = (x1 @ W2) * dinv ; aggregate only at selected nodes, fused w/ predictor
    k_gemm<<<(N + 63) / 64, 256, 0, stream>>>(x1, x1, N, N, W2, dinv, h);
    k_initout<<<(B + 255) / 256, 256, 0, stream>>>(pb, out, B);
    k_pred<<<(2 * B + 3) / 4, 256, 0, stream>>>(h, dinv, rowptr, srcs, b2, pw, uidx, jidx, U, B, out);
}

// Round 2
// 629.235 us; speedup vs baseline: 1.2996x; 1.2996x over previous
//
#include <hip/hip_runtime.h>

#define D 64
#define BSHIFT 10              // nodes per bucket = 1024
#define NBUK_MAX 256
#define T_TILE 6144            // edges per k_bin block (256 threads x 24)

// ---------------- degree histogram ----------------

__global__ void k_hist(const int* __restrict__ col, int E, int* __restrict__ count) {
    int e = blockIdx.x * 256 + threadIdx.x;
    if (e < E) atomicAdd(&count[col[e]], 1);
}

// ---------------- rowptr scan (1024 elems / block) ----------------

__global__ void k_scan1(const int* __restrict__ count, int n, int* __restrict__ partial) {
    __shared__ int sh[256];
    int base = blockIdx.x * 1024 + threadIdx.x * 4;
    int s = 0;
#pragma unroll
    for (int i = 0; i < 4; i++) { int idx = base + i; if (idx < n) s += count[idx]; }
    sh[threadIdx.x] = s; __syncthreads();
    for (int off = 1; off < 256; off <<= 1) {
        int v = (threadIdx.x >= (unsigned)off) ? sh[threadIdx.x - off] : 0;
        __syncthreads();
        sh[threadIdx.x] += v;
        __syncthreads();
    }
    if (threadIdx.x == 255) partial[blockIdx.x] = sh[255];
}

__global__ void k_scan2(const int* __restrict__ partial, int nb, int* __restrict__ basearr) {
    __shared__ int sh[256];
    int v = ((int)threadIdx.x < nb) ? partial[threadIdx.x] : 0;
    sh[threadIdx.x] = v; __syncthreads();
    for (int off = 1; off < 256; off <<= 1) {
        int u = (threadIdx.x >= (unsigned)off) ? sh[threadIdx.x - off] : 0;
        __syncthreads();
        sh[threadIdx.x] += u;
        __syncthreads();
    }
    if ((int)threadIdx.x < nb) basearr[threadIdx.x] = sh[threadIdx.x] - v;  // exclusive
}

__global__ void k_scan3(const int* __restrict__ count, int n, const int* __restrict__ basearr,
                        int* __restrict__ rowptr) {
    __shared__ int sh[256];
    int base = blockIdx.x * 1024 + threadIdx.x * 4;
    int c[4]; int s = 0;
#pragma unroll
    for (int i = 0; i < 4; i++) { int idx = base + i; c[i] = (idx < n) ? count[idx] : 0; s += c[i]; }
    sh[threadIdx.x] = s; __syncthreads();
    for (int off = 1; off < 256; off <<= 1) {
        int v = (threadIdx.x >= (unsigned)off) ? sh[threadIdx.x - off] : 0;
        __syncthreads();
        sh[threadIdx.x] += v;
        __syncthreads();
    }
    int run = basearr[blockIdx.x] + (sh[threadIdx.x] - s);
#pragma unroll
    for (int i = 0; i < 4; i++) {
        int idx = base + i;
        if (idx < n) { rowptr[idx] = run; run += c[i]; }
    }
}

// ---------------- dinv + bucket cursor init ----------------

__global__ void k_dinv(const int* __restrict__ count, const int* __restrict__ rowptr,
                       float* __restrict__ dinv, int* __restrict__ bbase, int N, int nbuk) {
    int i = blockIdx.x * 256 + threadIdx.x;
    if (i < N) dinv[i] = rsqrtf((float)(count[i] + 1));  // +1 self loop; always > 0
    if (i < nbuk) bbase[i] = rowptr[i << BSHIFT];        // bucket start in ebuf == srcs coords
}

// ---------------- bucket binning with LDS reorder (coalesced run writes) ----------------

__global__ __launch_bounds__(256) void k_bin(const int* __restrict__ row, const int* __restrict__ col,
                                             int E, int* __restrict__ bbase,
                                             unsigned long long* __restrict__ ebuf, int nbuk) {
    __shared__ int hist[NBUK_MAX];
    __shared__ int scan[NBUK_MAX];
    __shared__ int sexcl[NBUK_MAX];
    __shared__ int cur[NBUK_MAX];
    __shared__ int gbase[NBUK_MAX];
    __shared__ unsigned long long stage[T_TILE];   // 48 KB
    __shared__ unsigned char sbuk[T_TILE];         // 6 KB
    int tid = threadIdx.x;
    int tile0 = blockIdx.x * T_TILE;
    int cnt = min(T_TILE, E - tile0);

    hist[tid] = 0;
    __syncthreads();
    for (int i = tid; i < cnt; i += 256)
        atomicAdd(&hist[col[tile0 + i] >> BSHIFT], 1);
    __syncthreads();

    int v = hist[tid];
    scan[tid] = v; __syncthreads();
    for (int off = 1; off < 256; off <<= 1) {
        int u = (tid >= off) ? scan[tid - off] : 0;
        __syncthreads();
        scan[tid] += u;
        __syncthreads();
    }
    int excl = scan[tid] - v;
    sexcl[tid] = excl;
    cur[tid] = excl;
    gbase[tid] = (v > 0 && tid < nbuk) ? atomicAdd(&bbase[tid], v) : 0;
    __syncthreads();

    for (int i = tid; i < cnt; i += 256) {
        int r = row[tile0 + i];
        int c = col[tile0 + i];
        int b = c >> BSHIFT;
        int p = atomicAdd(&cur[b], 1);
        stage[p] = ((unsigned long long)(unsigned)c << 32) | (unsigned)r;
        sbuk[p] = (unsigned char)b;
    }
    __syncthreads();

    for (int i = tid; i < cnt; i += 256) {
        int b = sbuk[i];
        int gpos = gbase[b] + (i - sexcl[b]);
        ebuf[gpos] = stage[i];
    }
}

// ---------------- per-bucket CSR finalize (LDS cursors, L2-local writes) ----------------

__global__ __launch_bounds__(256) void k_csr(const unsigned long long* __restrict__ ebuf,
                                             const int* __restrict__ rowptr, int N,
                                             int* __restrict__ srcs) {
    __shared__ int lcur[1 << BSHIFT];  // 4 KB
    int c0 = blockIdx.x << BSHIFT;
    int cend = min(c0 + (1 << BSHIFT), N);
    int nn = cend - c0;
    for (int i = threadIdx.x; i < nn; i += 256) lcur[i] = rowptr[c0 + i];
    __syncthreads();
    int e0 = rowptr[c0], e1 = rowptr[cend];
    for (int j = e0 + threadIdx.x; j < e1; j += 256) {
        unsigned long long pk = ebuf[j];
        int r = (int)(unsigned)(pk & 0xffffffffull);
        int c = (int)(unsigned)(pk >> 32);
        int p = atomicAdd(&lcur[c - c0], 1);
        srcs[p] = r;
    }
}

// ---------------- dense: h[n][c] = dinv[n] * sum_k x[n][k] * W[k][c] ----------------

__global__ __launch_bounds__(256) void k_gemm(const float* __restrict__ xu, const float* __restrict__ xj,
                                              int U, int N, const float* __restrict__ W,
                                              const float* __restrict__ dinv, float* __restrict__ h) {
    __shared__ float Ws[64 * 64];
    __shared__ float Xs[64 * 68];
    int tid = threadIdx.x;
#pragma unroll
    for (int i = 0; i < 16; i++) Ws[tid + i * 256] = W[tid + i * 256];
    int n0 = blockIdx.x * 64;
#pragma unroll
    for (int i = 0; i < 4; i++) {
        int e4 = tid + i * 256;
        int nl = e4 >> 4, k4 = e4 & 15;
        int nn = n0 + nl;
        float4 v = make_float4(0.f, 0.f, 0.f, 0.f);
        if (nn < N) {
            const float* src = (nn < U) ? (xu + (size_t)nn * D) : (xj + (size_t)(nn - U) * D);
            v = *(const float4*)(src + k4 * 4);
        }
        *(float4*)(&Xs[nl * 68 + k4 * 4]) = v;
    }
    __syncthreads();
    int tx = tid & 15, ty = tid >> 4;
    float acc[4][4];
#pragma unroll
    for (int r = 0; r < 4; r++)
#pragma unroll
        for (int c = 0; c < 4; c++) acc[r][c] = 0.f;
#pragma unroll 16
    for (int k = 0; k < 64; k++) {
        float xv[4], wv[4];
#pragma unroll
        for (int r = 0; r < 4; r++) xv[r] = Xs[(ty * 4 + r) * 68 + k];
#pragma unroll
        for (int c = 0; c < 4; c++) wv[c] = Ws[k * 64 + tx * 4 + c];
#pragma unroll
        for (int r = 0; r < 4; r++)
#pragma unroll
            for (int c = 0; c < 4; c++) acc[r][c] += xv[r] * wv[c];
    }
#pragma unroll
    for (int r = 0; r < 4; r++) {
        int nn = n0 + ty * 4 + r;
        if (nn < N) {
            float sc = dinv[nn];
            float4 o = make_float4(acc[r][0] * sc, acc[r][1] * sc, acc[r][2] * sc, acc[r][3] * sc);
            *(float4*)(&h[(size_t)nn * D + tx * 4]) = o;
        }
    }
}

// ---------------- pull aggregation (full N) ----------------

__global__ __launch_bounds__(256) void k_agg(const float* __restrict__ hs, const float* __restrict__ dinv,
                                             const int* __restrict__ rowptr, const int* __restrict__ srcs,
                                             const float* __restrict__ bias, float* __restrict__ xout,
                                             int N, int do_relu) {
    int node = blockIdx.x * 4 + (threadIdx.x >> 6);
    int lane = threadIdx.x & 63;
    if (node >= N) return;
    float acc = hs[(size_t)node * D + lane];  // self loop (dinv[node] folded into hs)
    int e1 = rowptr[node + 1];
    for (int base0 = rowptr[node]; base0 < e1; base0 += 64) {
        int j = base0 + lane;
        int s = (j < e1) ? srcs[j] : 0;
        int cnt = min(64, e1 - base0);
        for (int i = 0; i < cnt; i++) {
            int si = __shfl(s, i, 64);
            acc += hs[(size_t)si * D + lane];
        }
    }
    acc = acc * dinv[node] + bias[lane];
    if (do_relu) acc = fmaxf(acc, 0.f);
    xout[(size_t)node * D + lane] = acc;
}

// ---------------- fused layer-2 selected-node aggregation + prediction ----------------

__global__ void k_initout(const float* __restrict__ pb, float* __restrict__ out, int B) {
    int i = blockIdx.x * 256 + threadIdx.x;
    if (i < B) out[i] = pb[0];
}

__global__ __launch_bounds__(256) void k_pred(const float* __restrict__ hs2, const float* __restrict__ dinv,
                                              const int* __restrict__ rowptr, const int* __restrict__ srcs,
                                              const float* __restrict__ b2, const float* __restrict__ pw,
                                              const int* __restrict__ uidx, const int* __restrict__ jidx,
                                              int U, int B, float* __restrict__ out) {
    int wid = blockIdx.x * 4 + (threadIdx.x >> 6);
    int lane = threadIdx.x & 63;
    if (wid >= 2 * B) return;
    int isU = (wid < B);
    int b = isU ? wid : wid - B;
    int c = isU ? uidx[b] : U + jidx[b];
    float acc = hs2[(size_t)c * D + lane];
    int e1 = rowptr[c + 1];
    for (int base0 = rowptr[c]; base0 < e1; base0 += 64) {
        int j = base0 + lane;
        int s = (j < e1) ? srcs[j] : 0;
        int cnt = min(64, e1 - base0);
        for (int i = 0; i < cnt; i++) {
            int si = __shfl(s, i, 64);
            acc += hs2[(size_t)si * D + lane];
        }
    }
    acc = acc * dinv[c] + b2[lane];
    float v = acc * pw[(isU ? 0 : 64) + lane];
#pragma unroll
    for (int off = 32; off >= 1; off >>= 1) v += __shfl_xor(v, off, 64);
    if (lane == 0) atomicAdd(&out[b], v);
}

// ---------------- host ----------------

extern "C" void kernel_launch(void* const* d_in, const int* in_sizes, int n_in,
                              void* d_out, int out_size, void* d_ws, size_t ws_size,
                              hipStream_t stream) {
    const int*   edge = (const int*)d_in[0];
    const int*   uidx = (const int*)d_in[1];
    const int*   jidx = (const int*)d_in[2];
    const float* xu   = (const float*)d_in[3];
    const float* xj   = (const float*)d_in[4];
    const float* W1   = (const float*)d_in[5];
    const float* b1   = (const float*)d_in[6];
    const float* W2   = (const float*)d_in[7];
    const float* b2   = (const float*)d_in[8];
    const float* pw   = (const float*)d_in[9];
    const float* pb   = (const float*)d_in[10];
    float* out = (float*)d_out;

    int E = in_sizes[0] / 2;
    int B = in_sizes[1];
    int U = in_sizes[3] / D;
    int J = in_sizes[4] / D;
    int N = U + J;
    int nbuk = (N + (1 << BSHIFT) - 1) >> BSHIFT;   // 196 for N=200000; must be <= 256
    const int* row = edge;       // sources
    const int* col = edge + E;   // targets

    char* p = (char*)d_ws;
    auto alloc = [&](size_t bytes) -> void* {
        void* q = (void*)p;
        p += (bytes + 255) / 256 * 256;
        return q;
    };
    int*   count   = (int*)alloc((size_t)(N + 1) * 4);
    int*   rowptr  = (int*)alloc((size_t)(N + 1) * 4);
    int*   partial = (int*)alloc(256 * 4);
    int*   basearr = (int*)alloc(256 * 4);
    float* dinv    = (float*)alloc((size_t)N * 4);
    int*   bbase   = (int*)alloc(256 * 4);
    int*   srcs    = (int*)alloc((size_t)E * 4);
    float* h       = (float*)alloc((size_t)N * D * 4);  // also aliased as ebuf before GEMMs
    float* x1      = (float*)alloc((size_t)N * D * 4);
    unsigned long long* ebuf = (unsigned long long*)h;  // E*8 <= N*D*4 required

    hipMemsetAsync(count, 0, (size_t)(N + 1) * 4, stream);
    k_hist<<<(E + 255) / 256, 256, 0, stream>>>(col, E, count);

    int n_scan = N + 1;
    int NB = (n_scan + 1023) / 1024;
    k_scan1<<<NB, 256, 0, stream>>>(count, n_scan, partial);
    k_scan2<<<1, 256, 0, stream>>>(partial, NB, basearr);
    k_scan3<<<NB, 256, 0, stream>>>(count, n_scan, basearr, rowptr);
    k_dinv<<<(N + 255) / 256, 256, 0, stream>>>(count, rowptr, dinv, bbase, N, nbuk);

    // CSR build: bucketed binning (coalesced runs) then per-bucket LDS-cursor scatter
    k_bin<<<(E + T_TILE - 1) / T_TILE, 256, 0, stream>>>(row, col, E, bbase, ebuf, nbuk);
    k_csr<<<nbuk, 256, 0, stream>>>(ebuf, rowptr, N, srcs);

    // layer 1: hs = (x @ W1) * dinv ; x1 = relu(dinv*(hs_self + sum) + b1)
    k_gemm<<<(N + 63) / 64, 256, 0, stream>>>(xu, xj, U, N, W1, dinv, h);
    k_agg<<<(N + 3) / 4, 256, 0, stream>>>(h, dinv, rowptr, srcs, b1, x1, N, 1);

    // layer 2: hs2 = (x1 @ W2) * dinv ; aggregate only at selected nodes, fused w/ predictor
    k_gemm<<<(N + 63) / 64, 256, 0, stream>>>(x1, x1, N, N, W2, dinv, h);
    k_initout<<<(B + 255) / 256, 256, 0, stream>>>(pb, out, B);
    k_pred<<<(2 * B + 3) / 4, 256, 0, stream>>>(h, dinv, rowptr, srcs, b2, pw, uidx, jidx, U, B, out);
}

// Round 3
// 533.100 us; speedup vs baseline: 1.5339x; 1.1803x over previous
//
#include <hip/hip_runtime.h>

#define D 64
#define BSHIFT 10              // nodes per bucket = 1024
#define BMASK ((1 << BSHIFT) - 1)
#define NBUK_MAX 256
#define T_TILE 6144            // edges per k_bin block (256 threads x 24)

// ---------------- degree histogram ----------------

__global__ void k_hist(const int* __restrict__ col, int E, int* __restrict__ count) {
    int base = (blockIdx.x * 256 + threadIdx.x) * 4;
    if (base + 3 < E) {
        int4 c = *(const int4*)(col + base);
        atomicAdd(&count[c.x], 1);
        atomicAdd(&count[c.y], 1);
        atomicAdd(&count[c.z], 1);
        atomicAdd(&count[c.w], 1);
    } else {
        for (int k = base; k < E; k++) atomicAdd(&count[col[k]], 1);
    }
}

// ---------------- rowptr scan (1024 elems / block) ----------------

__global__ void k_scan1(const int* __restrict__ count, int n, int* __restrict__ partial) {
    __shared__ int sh[256];
    int base = blockIdx.x * 1024 + threadIdx.x * 4;
    int s = 0;
#pragma unroll
    for (int i = 0; i < 4; i++) { int idx = base + i; if (idx < n) s += count[idx]; }
    sh[threadIdx.x] = s; __syncthreads();
    for (int off = 1; off < 256; off <<= 1) {
        int v = (threadIdx.x >= (unsigned)off) ? sh[threadIdx.x - off] : 0;
        __syncthreads();
        sh[threadIdx.x] += v;
        __syncthreads();
    }
    if (threadIdx.x == 255) partial[blockIdx.x] = sh[255];
}

__global__ void k_scan2(const int* __restrict__ partial, int nb, int* __restrict__ basearr) {
    __shared__ int sh[256];
    int v = ((int)threadIdx.x < nb) ? partial[threadIdx.x] : 0;
    sh[threadIdx.x] = v; __syncthreads();
    for (int off = 1; off < 256; off <<= 1) {
        int u = (threadIdx.x >= (unsigned)off) ? sh[threadIdx.x - off] : 0;
        __syncthreads();
        sh[threadIdx.x] += u;
        __syncthreads();
    }
    if ((int)threadIdx.x < nb) basearr[threadIdx.x] = sh[threadIdx.x] - v;  // exclusive
}

__global__ void k_scan3(const int* __restrict__ count, int n, const int* __restrict__ basearr,
                        int* __restrict__ rowptr) {
    __shared__ int sh[256];
    int base = blockIdx.x * 1024 + threadIdx.x * 4;
    int c[4]; int s = 0;
#pragma unroll
    for (int i = 0; i < 4; i++) { int idx = base + i; c[i] = (idx < n) ? count[idx] : 0; s += c[i]; }
    sh[threadIdx.x] = s; __syncthreads();
    for (int off = 1; off < 256; off <<= 1) {
        int v = (threadIdx.x >= (unsigned)off) ? sh[threadIdx.x - off] : 0;
        __syncthreads();
        sh[threadIdx.x] += v;
        __syncthreads();
    }
    int run = basearr[blockIdx.x] + (sh[threadIdx.x] - s);
#pragma unroll
    for (int i = 0; i < 4; i++) {
        int idx = base + i;
        if (idx < n) { rowptr[idx] = run; run += c[i]; }
    }
}

// ---------------- dinv + bucket cursor init ----------------

__global__ void k_dinv(const int* __restrict__ count, const int* __restrict__ rowptr,
                       float* __restrict__ dinv, int* __restrict__ bbase, int N, int nbuk) {
    int i = blockIdx.x * 256 + threadIdx.x;
    if (i < N) dinv[i] = rsqrtf((float)(count[i] + 1));  // +1 self loop; always > 0
    if (i < nbuk) bbase[i] = rowptr[i << BSHIFT];        // bucket start in ebuf == srcs coords
}

// ---------------- bucket binning with LDS reorder (coalesced run writes) ----------------
// packed entry: (c & BMASK) << 18 | r   — requires N <= 2^18 (N=200000 here)

__global__ __launch_bounds__(256) void k_bin(const int* __restrict__ row, const int* __restrict__ col,
                                             int E, int* __restrict__ bbase,
                                             unsigned* __restrict__ ebuf, int nbuk) {
    __shared__ int hist[NBUK_MAX];
    __shared__ int scan[NBUK_MAX];
    __shared__ int sexcl[NBUK_MAX];
    __shared__ int cur[NBUK_MAX];
    __shared__ int gbase[NBUK_MAX];
    __shared__ unsigned stage[T_TILE];     // 24 KB
    __shared__ unsigned char sbuk[T_TILE]; // 6 KB
    int tid = threadIdx.x;
    int tile0 = blockIdx.x * T_TILE;
    int cnt = min(T_TILE, E - tile0);

    hist[tid] = 0;
    __syncthreads();
    for (int i = tid; i < cnt; i += 256)
        atomicAdd(&hist[col[tile0 + i] >> BSHIFT], 1);
    __syncthreads();

    int v = hist[tid];
    scan[tid] = v; __syncthreads();
    for (int off = 1; off < 256; off <<= 1) {
        int u = (tid >= off) ? scan[tid - off] : 0;
        __syncthreads();
        scan[tid] += u;
        __syncthreads();
    }
    int excl = scan[tid] - v;
    sexcl[tid] = excl;
    cur[tid] = excl;
    gbase[tid] = (v > 0 && tid < nbuk) ? atomicAdd(&bbase[tid], v) : 0;
    __syncthreads();

    for (int i = tid; i < cnt; i += 256) {
        int r = row[tile0 + i];
        int c = col[tile0 + i];
        int b = c >> BSHIFT;
        int p = atomicAdd(&cur[b], 1);
        stage[p] = ((unsigned)(c & BMASK) << 18) | (unsigned)r;
        sbuk[p] = (unsigned char)b;
    }
    __syncthreads();

    for (int i = tid; i < cnt; i += 256) {
        int b = sbuk[i];
        int gpos = gbase[b] + (i - sexcl[b]);
        ebuf[gpos] = stage[i];
    }
}

// ---------------- per-bucket CSR finalize (LDS cursors, L2-local writes) ----------------

__global__ __launch_bounds__(256) void k_csr(const unsigned* __restrict__ ebuf,
                                             const int* __restrict__ rowptr, int N,
                                             int* __restrict__ srcs) {
    __shared__ int lcur[1 << BSHIFT];  // 4 KB
    int c0 = blockIdx.x << BSHIFT;
    int cend = min(c0 + (1 << BSHIFT), N);
    int nn = cend - c0;
    for (int i = threadIdx.x; i < nn; i += 256) lcur[i] = rowptr[c0 + i];
    __syncthreads();
    int e0 = rowptr[c0], e1 = rowptr[cend];
    for (int j = e0 + threadIdx.x; j < e1; j += 256) {
        unsigned pk = ebuf[j];
        int p = atomicAdd(&lcur[pk >> 18], 1);
        srcs[p] = (int)(pk & 0x3ffffu);
    }
}

// ---------------- dense: h[n][c] = dinv[n] * sum_k x[n][k] * W[k][c] ----------------

__global__ __launch_bounds__(256) void k_gemm(const float* __restrict__ xu, const float* __restrict__ xj,
                                              int U, int N, const float* __restrict__ W,
                                              const float* __restrict__ dinv, float* __restrict__ h) {
    __shared__ float Ws[64 * 64];
    __shared__ float Xs[64 * 68];
    int tid = threadIdx.x;
#pragma unroll
    for (int i = 0; i < 16; i++) Ws[tid + i * 256] = W[tid + i * 256];
    int n0 = blockIdx.x * 64;
#pragma unroll
    for (int i = 0; i < 4; i++) {
        int e4 = tid + i * 256;
        int nl = e4 >> 4, k4 = e4 & 15;
        int nn = n0 + nl;
        float4 v = make_float4(0.f, 0.f, 0.f, 0.f);
        if (nn < N) {
            const float* src = (nn < U) ? (xu + (size_t)nn * D) : (xj + (size_t)(nn - U) * D);
            v = *(const float4*)(src + k4 * 4);
        }
        *(float4*)(&Xs[nl * 68 + k4 * 4]) = v;
    }
    __syncthreads();
    int tx = tid & 15, ty = tid >> 4;
    float acc[4][4];
#pragma unroll
    for (int r = 0; r < 4; r++)
#pragma unroll
        for (int c = 0; c < 4; c++) acc[r][c] = 0.f;
#pragma unroll 16
    for (int k = 0; k < 64; k++) {
        float xv[4], wv[4];
#pragma unroll
        for (int r = 0; r < 4; r++) xv[r] = Xs[(ty * 4 + r) * 68 + k];
#pragma unroll
        for (int c = 0; c < 4; c++) wv[c] = Ws[k * 64 + tx * 4 + c];
#pragma unroll
        for (int r = 0; r < 4; r++)
#pragma unroll
            for (int c = 0; c < 4; c++) acc[r][c] += xv[r] * wv[c];
    }
#pragma unroll
    for (int r = 0; r < 4; r++) {
        int nn = n0 + ty * 4 + r;
        if (nn < N) {
            float sc = dinv[nn];
            float4 o = make_float4(acc[r][0] * sc, acc[r][1] * sc, acc[r][2] * sc, acc[r][3] * sc);
            *(float4*)(&h[(size_t)nn * D + tx * 4]) = o;
        }
    }
}

// ---------------- pull aggregation (full N), 4-edge-parallel float4 gathers ----------------
// wave = 1 node; lane = g*16+t; group g handles edge slots i === g (mod 4);
// lane t covers features [4t, 4t+4). Cross-group sum via shfl_xor(16|32).

__global__ __launch_bounds__(256) void k_agg(const float* __restrict__ hs, const float* __restrict__ dinv,
                                             const int* __restrict__ rowptr, const int* __restrict__ srcs,
                                             const float* __restrict__ bias, float* __restrict__ xout,
                                             int N, int do_relu) {
    int node = blockIdx.x * 4 + (threadIdx.x >> 6);
    int lane = threadIdx.x & 63;
    int g = lane >> 4, t = lane & 15;
    if (node >= N) return;
    float4 acc = make_float4(0.f, 0.f, 0.f, 0.f);
    int e0 = rowptr[node], e1 = rowptr[node + 1];
    for (int base0 = e0; base0 < e1; base0 += 64) {
        int j = base0 + lane;
        int s = (j < e1) ? srcs[j] : 0;
        int cnt = min(64, e1 - base0);
        int iters = (cnt + 3) >> 2;
        for (int ii = 0; ii < iters; ii++) {
            int i = ii * 4 + g;
            int si = __shfl(s, (i < cnt) ? i : 0, 64);
            if (i < cnt) {
                float4 v = *(const float4*)(hs + (size_t)si * D + t * 4);
                acc.x += v.x; acc.y += v.y; acc.z += v.z; acc.w += v.w;
            }
        }
    }
    // cross-group reduction
    acc.x += __shfl_xor(acc.x, 16, 64); acc.x += __shfl_xor(acc.x, 32, 64);
    acc.y += __shfl_xor(acc.y, 16, 64); acc.y += __shfl_xor(acc.y, 32, 64);
    acc.z += __shfl_xor(acc.z, 16, 64); acc.z += __shfl_xor(acc.z, 32, 64);
    acc.w += __shfl_xor(acc.w, 16, 64); acc.w += __shfl_xor(acc.w, 32, 64);
    float4 self = *(const float4*)(hs + (size_t)node * D + t * 4);
    float4 b4 = *(const float4*)(bias + t * 4);
    float dv = dinv[node];
    float4 o;
    o.x = (acc.x + self.x) * dv + b4.x;
    o.y = (acc.y + self.y) * dv + b4.y;
    o.z = (acc.z + self.z) * dv + b4.z;
    o.w = (acc.w + self.w) * dv + b4.w;
    if (do_relu) {
        o.x = fmaxf(o.x, 0.f); o.y = fmaxf(o.y, 0.f);
        o.z = fmaxf(o.z, 0.f); o.w = fmaxf(o.w, 0.f);
    }
    if (g == 0) *(float4*)(xout + (size_t)node * D + t * 4) = o;
}

// ---------------- fused layer-2 selected-node aggregation + prediction ----------------

__global__ void k_initout(const float* __restrict__ pb, float* __restrict__ out, int B) {
    int i = blockIdx.x * 256 + threadIdx.x;
    if (i < B) out[i] = pb[0];
}

__global__ __launch_bounds__(256) void k_pred(const float* __restrict__ hs2, const float* __restrict__ dinv,
                                              const int* __restrict__ rowptr, const int* __restrict__ srcs,
                                              const float* __restrict__ b2, const float* __restrict__ pw,
                                              const int* __restrict__ uidx, const int* __restrict__ jidx,
                                              int U, int B, float* __restrict__ out) {
    int wid = blockIdx.x * 4 + (threadIdx.x >> 6);
    int lane = threadIdx.x & 63;
    int g = lane >> 4, t = lane & 15;
    if (wid >= 2 * B) return;
    int isU = (wid < B);
    int b = isU ? wid : wid - B;
    int c = isU ? uidx[b] : U + jidx[b];
    float4 acc = make_float4(0.f, 0.f, 0.f, 0.f);
    int e0 = rowptr[c], e1 = rowptr[c + 1];
    for (int base0 = e0; base0 < e1; base0 += 64) {
        int j = base0 + lane;
        int s = (j < e1) ? srcs[j] : 0;
        int cnt = min(64, e1 - base0);
        int iters = (cnt + 3) >> 2;
        for (int ii = 0; ii < iters; ii++) {
            int i = ii * 4 + g;
            int si = __shfl(s, (i < cnt) ? i : 0, 64);
            if (i < cnt) {
                float4 v = *(const float4*)(hs2 + (size_t)si * D + t * 4);
                acc.x += v.x; acc.y += v.y; acc.z += v.z; acc.w += v.w;
            }
        }
    }
    acc.x += __shfl_xor(acc.x, 16, 64); acc.x += __shfl_xor(acc.x, 32, 64);
    acc.y += __shfl_xor(acc.y, 16, 64); acc.y += __shfl_xor(acc.y, 32, 64);
    acc.z += __shfl_xor(acc.z, 16, 64); acc.z += __shfl_xor(acc.z, 32, 64);
    acc.w += __shfl_xor(acc.w, 16, 64); acc.w += __shfl_xor(acc.w, 32, 64);
    float4 self = *(const float4*)(hs2 + (size_t)c * D + t * 4);
    float4 b4 = *(const float4*)(b2 + t * 4);
    float dv = dinv[c];
    float4 w4 = *(const float4*)(pw + (isU ? 0 : 64) + t * 4);
    float vx = ((acc.x + self.x) * dv + b4.x) * w4.x
             + ((acc.y + self.y) * dv + b4.y) * w4.y
             + ((acc.z + self.z) * dv + b4.z) * w4.z
             + ((acc.w + self.w) * dv + b4.w) * w4.w;
    vx += __shfl_xor(vx, 1, 64); vx += __shfl_xor(vx, 2, 64);
    vx += __shfl_xor(vx, 4, 64); vx += __shfl_xor(vx, 8, 64);
    if (lane == 0) atomicAdd(&out[b], vx);
}

// ---------------- host ----------------

extern "C" void kernel_launch(void* const* d_in, const int* in_sizes, int n_in,
                              void* d_out, int out_size, void* d_ws, size_t ws_size,
                              hipStream_t stream) {
    const int*   edge = (const int*)d_in[0];
    const int*   uidx = (const int*)d_in[1];
    const int*   jidx = (const int*)d_in[2];
    const float* xu   = (const float*)d_in[3];
    const float* xj   = (const float*)d_in[4];
    const float* W1   = (const float*)d_in[5];
    const float* b1   = (const float*)d_in[6];
    const float* W2   = (const float*)d_in[7];
    const float* b2   = (const float*)d_in[8];
    const float* pw   = (const float*)d_in[9];
    const float* pb   = (const float*)d_in[10];
    float* out = (float*)d_out;

    int E = in_sizes[0] / 2;
    int B = in_sizes[1];
    int U = in_sizes[3] / D;
    int J = in_sizes[4] / D;
    int N = U + J;
    int nbuk = (N + (1 << BSHIFT) - 1) >> BSHIFT;   // 196 for N=200000; must be <= 256
    const int* row = edge;       // sources
    const int* col = edge + E;   // targets

    char* p = (char*)d_ws;
    auto alloc = [&](size_t bytes) -> void* {
        void* q = (void*)p;
        p += (bytes + 255) / 256 * 256;
        return q;
    };
    int*   count   = (int*)alloc((size_t)(N + 1) * 4);
    int*   rowptr  = (int*)alloc((size_t)(N + 1) * 4);
    int*   partial = (int*)alloc(256 * 4);
    int*   basearr = (int*)alloc(256 * 4);
    float* dinv    = (float*)alloc((size_t)N * 4);
    int*   bbase   = (int*)alloc(256 * 4);
    int*   srcs    = (int*)alloc((size_t)E * 4);
    float* h       = (float*)alloc((size_t)N * D * 4);  // aliased as ebuf before GEMMs
    float* x1      = (float*)alloc((size_t)N * D * 4);
    unsigned* ebuf = (unsigned*)h;                      // E*4 <= N*D*4 required

    hipMemsetAsync(count, 0, (size_t)(N + 1) * 4, stream);
    k_hist<<<(E / 4 + 255) / 256, 256, 0, stream>>>(col, E, count);

    int n_scan = N + 1;
    int NB = (n_scan + 1023) / 1024;
    k_scan1<<<NB, 256, 0, stream>>>(count, n_scan, partial);
    k_scan2<<<1, 256, 0, stream>>>(partial, NB, basearr);
    k_scan3<<<NB, 256, 0, stream>>>(count, n_scan, basearr, rowptr);
    k_dinv<<<(N + 255) / 256, 256, 0, stream>>>(count, rowptr, dinv, bbase, N, nbuk);

    // CSR build: bucketed binning (coalesced packed runs) then per-bucket LDS-cursor scatter
    k_bin<<<(E + T_TILE - 1) / T_TILE, 256, 0, stream>>>(row, col, E, bbase, ebuf, nbuk);
    k_csr<<<nbuk, 256, 0, stream>>>(ebuf, rowptr, N, srcs);

    // layer 1: hs = (x @ W1) * dinv ; x1 = relu(dinv*(hs_self + sum) + b1)
    k_gemm<<<(N + 63) / 64, 256, 0, stream>>>(xu, xj, U, N, W1, dinv, h);
    k_agg<<<(N + 3) / 4, 256, 0, stream>>>(h, dinv, rowptr, srcs, b1, x1, N, 1);

    // layer 2: hs2 = (x1 @ W2) * dinv ; aggregate only at selected nodes, fused w/ predictor
    k_gemm<<<(N + 63) / 64, 256, 0, stream>>>(x1, x1, N, N, W2, dinv, h);
    k_initout<<<(B + 255) / 256, 256, 0, stream>>>(pb, out, B);
    k_pred<<<(2 * B + 3) / 4, 256, 0, stream>>>(h, dinv, rowptr, srcs, b2, pw, uidx, jidx, U, B, out);
}

// Round 4
// 427.688 us; speedup vs baseline: 1.9120x; 1.2465x over previous
//
#include <hip/hip_runtime.h>

#define D 64
#define BSHIFT 10              // nodes per bucket = 1024
#define BMASK ((1 << BSHIFT) - 1)
#define NBUK_MAX 256
#define T_TILE 6144            // edges per k_bin block (256 threads x 24)

// ---------------- per-bucket edge counts (LDS-privatized) ----------------

__global__ __launch_bounds__(256) void k_bukcnt(const int* __restrict__ col, int E,
                                                int* __restrict__ bukcnt) {
    __shared__ int h[NBUK_MAX];
    h[threadIdx.x] = 0;
    __syncthreads();
    int stride = gridDim.x * 256 * 4;
    for (int base = (blockIdx.x * 256 + threadIdx.x) * 4; base < E; base += stride) {
        if (base + 3 < E) {
            int4 c = *(const int4*)(col + base);
            atomicAdd(&h[c.x >> BSHIFT], 1);
            atomicAdd(&h[c.y >> BSHIFT], 1);
            atomicAdd(&h[c.z >> BSHIFT], 1);
            atomicAdd(&h[c.w >> BSHIFT], 1);
        } else {
            for (int k = base; k < E; k++) atomicAdd(&h[col[k] >> BSHIFT], 1);
        }
    }
    __syncthreads();
    int v = h[threadIdx.x];
    if (v) atomicAdd(&bukcnt[threadIdx.x], v);
}

// ---------------- bucket base scan (single block) ----------------

__global__ void k_bukscan(const int* __restrict__ bukcnt, int nbuk, int E,
                          int* __restrict__ bb0, int* __restrict__ bbase,
                          int* __restrict__ rowptr, int N) {
    __shared__ int sh[256];
    int tid = threadIdx.x;
    int v = (tid < nbuk) ? bukcnt[tid] : 0;
    sh[tid] = v; __syncthreads();
    for (int off = 1; off < 256; off <<= 1) {
        int u = (tid >= off) ? sh[tid - off] : 0;
        __syncthreads();
        sh[tid] += u;
        __syncthreads();
    }
    int excl = sh[tid] - v;
    if (tid < nbuk) { bb0[tid] = excl; bbase[tid] = excl; }
    if (tid == 0) { bb0[nbuk] = E; rowptr[N] = E; }
}

// ---------------- bucket binning with LDS reorder (coalesced run writes) ----------------
// packed entry: (c & BMASK) << 18 | r   — requires N <= 2^18 (N=200000 here)

__global__ __launch_bounds__(256) void k_bin(const int* __restrict__ row, const int* __restrict__ col,
                                             int E, int* __restrict__ bbase,
                                             unsigned* __restrict__ ebuf, int nbuk) {
    __shared__ int hist[NBUK_MAX];
    __shared__ int scan[NBUK_MAX];
    __shared__ int sexcl[NBUK_MAX];
    __shared__ int cur[NBUK_MAX];
    __shared__ int gbase[NBUK_MAX];
    __shared__ unsigned stage[T_TILE];     // 24 KB
    __shared__ unsigned char sbuk[T_TILE]; // 6 KB
    int tid = threadIdx.x;
    int tile0 = blockIdx.x * T_TILE;
    int cnt = min(T_TILE, E - tile0);

    hist[tid] = 0;
    __syncthreads();
    for (int i = tid; i < cnt; i += 256)
        atomicAdd(&hist[col[tile0 + i] >> BSHIFT], 1);
    __syncthreads();

    int v = hist[tid];
    scan[tid] = v; __syncthreads();
    for (int off = 1; off < 256; off <<= 1) {
        int u = (tid >= off) ? scan[tid - off] : 0;
        __syncthreads();
        scan[tid] += u;
        __syncthreads();
    }
    int excl = scan[tid] - v;
    sexcl[tid] = excl;
    cur[tid] = excl;
    gbase[tid] = (v > 0 && tid < nbuk) ? atomicAdd(&bbase[tid], v) : 0;
    __syncthreads();

    for (int i = tid; i < cnt; i += 256) {
        int r = row[tile0 + i];
        int c = col[tile0 + i];
        int b = c >> BSHIFT;
        int p = atomicAdd(&cur[b], 1);
        stage[p] = ((unsigned)(c & BMASK) << 18) | (unsigned)r;
        sbuk[p] = (unsigned char)b;
    }
    __syncthreads();

    for (int i = tid; i < cnt; i += 256) {
        int b = sbuk[i];
        int gpos = gbase[b] + (i - sexcl[b]);
        ebuf[gpos] = stage[i];
    }
}

// ---------------- per-bucket degree count + rowptr + dinv + CSR scatter ----------------

__global__ __launch_bounds__(256) void k_csr2(const unsigned* __restrict__ ebuf,
                                              const int* __restrict__ bb0, int N,
                                              int* __restrict__ rowptr, float* __restrict__ dinv,
                                              int* __restrict__ srcs) {
    __shared__ int lcnt[1 << BSHIFT];  // 4 KB
    __shared__ int lcur[1 << BSHIFT];  // 4 KB
    __shared__ int ssum[256];
    int tid = threadIdx.x;
    int c0 = blockIdx.x << BSHIFT;
    int nn = min(1 << BSHIFT, N - c0);
    int e0 = bb0[blockIdx.x], e1 = bb0[blockIdx.x + 1];

    for (int i = tid; i < (1 << BSHIFT); i += 256) lcnt[i] = 0;
    __syncthreads();
    for (int j = e0 + tid; j < e1; j += 256)
        atomicAdd(&lcnt[ebuf[j] >> 18], 1);
    __syncthreads();

    // scan 1024 LDS counters (thread handles 4 consecutive)
    int c[4]; int s = 0;
#pragma unroll
    for (int i = 0; i < 4; i++) { c[i] = lcnt[tid * 4 + i]; s += c[i]; }
    ssum[tid] = s; __syncthreads();
    for (int off = 1; off < 256; off <<= 1) {
        int u = (tid >= off) ? ssum[tid - off] : 0;
        __syncthreads();
        ssum[tid] += u;
        __syncthreads();
    }
    int run = ssum[tid] - s;  // exclusive
#pragma unroll
    for (int i = 0; i < 4; i++) {
        int idx = tid * 4 + i;
        lcur[idx] = run;
        if (idx < nn) {
            rowptr[c0 + idx] = e0 + run;
            dinv[c0 + idx] = rsqrtf((float)(c[i] + 1));  // +1 self loop
        }
        run += c[i];
    }
    __syncthreads();

    for (int j = e0 + tid; j < e1; j += 256) {
        unsigned pk = ebuf[j];
        int p = atomicAdd(&lcur[pk >> 18], 1);
        srcs[e0 + p] = (int)(pk & 0x3ffffu);
    }
}

// ---------------- dense: h[n][c] = dinv[n] * sum_k x[n][k] * W[k][c] ----------------

__global__ __launch_bounds__(256) void k_gemm(const float* __restrict__ xu, const float* __restrict__ xj,
                                              int U, int N, const float* __restrict__ W,
                                              const float* __restrict__ dinv, float* __restrict__ h) {
    __shared__ float Ws[64 * 64];
    __shared__ float Xs[64 * 68];
    int tid = threadIdx.x;
#pragma unroll
    for (int i = 0; i < 16; i++) Ws[tid + i * 256] = W[tid + i * 256];
    int n0 = blockIdx.x * 64;
#pragma unroll
    for (int i = 0; i < 4; i++) {
        int e4 = tid + i * 256;
        int nl = e4 >> 4, k4 = e4 & 15;
        int nn = n0 + nl;
        float4 v = make_float4(0.f, 0.f, 0.f, 0.f);
        if (nn < N) {
            const float* src = (nn < U) ? (xu + (size_t)nn * D) : (xj + (size_t)(nn - U) * D);
            v = *(const float4*)(src + k4 * 4);
        }
        *(float4*)(&Xs[nl * 68 + k4 * 4]) = v;
    }
    __syncthreads();
    int tx = tid & 15, ty = tid >> 4;
    float acc[4][4];
#pragma unroll
    for (int r = 0; r < 4; r++)
#pragma unroll
        for (int c = 0; c < 4; c++) acc[r][c] = 0.f;
#pragma unroll 16
    for (int k = 0; k < 64; k++) {
        float xv[4], wv[4];
#pragma unroll
        for (int r = 0; r < 4; r++) xv[r] = Xs[(ty * 4 + r) * 68 + k];
#pragma unroll
        for (int c = 0; c < 4; c++) wv[c] = Ws[k * 64 + tx * 4 + c];
#pragma unroll
        for (int r = 0; r < 4; r++)
#pragma unroll
            for (int c = 0; c < 4; c++) acc[r][c] += xv[r] * wv[c];
    }
#pragma unroll
    for (int r = 0; r < 4; r++) {
        int nn = n0 + ty * 4 + r;
        if (nn < N) {
            float sc = dinv[nn];
            float4 o = make_float4(acc[r][0] * sc, acc[r][1] * sc, acc[r][2] * sc, acc[r][3] * sc);
            *(float4*)(&h[(size_t)nn * D + tx * 4]) = o;
        }
    }
}

// ---------------- pull aggregation (full N), 4-edge-parallel float4 gathers ----------------

__global__ __launch_bounds__(256) void k_agg(const float* __restrict__ hs, const float* __restrict__ dinv,
                                             const int* __restrict__ rowptr, const int* __restrict__ srcs,
                                             const float* __restrict__ bias, float* __restrict__ xout,
                                             int N, int do_relu) {
    int node = blockIdx.x * 4 + (threadIdx.x >> 6);
    int lane = threadIdx.x & 63;
    int g = lane >> 4, t = lane & 15;
    if (node >= N) return;
    float4 acc = make_float4(0.f, 0.f, 0.f, 0.f);
    int e0 = rowptr[node], e1 = rowptr[node + 1];
    for (int base0 = e0; base0 < e1; base0 += 64) {
        int j = base0 + lane;
        int s = (j < e1) ? srcs[j] : 0;
        int cnt = min(64, e1 - base0);
        int iters = (cnt + 3) >> 2;
        for (int ii = 0; ii < iters; ii++) {
            int i = ii * 4 + g;
            int si = __shfl(s, (i < cnt) ? i : 0, 64);
            if (i < cnt) {
                float4 v = *(const float4*)(hs + (size_t)si * D + t * 4);
                acc.x += v.x; acc.y += v.y; acc.z += v.z; acc.w += v.w;
            }
        }
    }
    acc.x += __shfl_xor(acc.x, 16, 64); acc.x += __shfl_xor(acc.x, 32, 64);
    acc.y += __shfl_xor(acc.y, 16, 64); acc.y += __shfl_xor(acc.y, 32, 64);
    acc.z += __shfl_xor(acc.z, 16, 64); acc.z += __shfl_xor(acc.z, 32, 64);
    acc.w += __shfl_xor(acc.w, 16, 64); acc.w += __shfl_xor(acc.w, 32, 64);
    float4 self = *(const float4*)(hs + (size_t)node * D + t * 4);
    float4 b4 = *(const float4*)(bias + t * 4);
    float dv = dinv[node];
    float4 o;
    o.x = (acc.x + self.x) * dv + b4.x;
    o.y = (acc.y + self.y) * dv + b4.y;
    o.z = (acc.z + self.z) * dv + b4.z;
    o.w = (acc.w + self.w) * dv + b4.w;
    if (do_relu) {
        o.x = fmaxf(o.x, 0.f); o.y = fmaxf(o.y, 0.f);
        o.z = fmaxf(o.z, 0.f); o.w = fmaxf(o.w, 0.f);
    }
    if (g == 0) *(float4*)(xout + (size_t)node * D + t * 4) = o;
}

// ---------------- fused layer-2 selected-node aggregation + prediction ----------------

__global__ void k_initout(const float* __restrict__ pb, float* __restrict__ out, int B) {
    int i = blockIdx.x * 256 + threadIdx.x;
    if (i < B) out[i] = pb[0];
}

__global__ __launch_bounds__(256) void k_pred(const float* __restrict__ hs2, const float* __restrict__ dinv,
                                              const int* __restrict__ rowptr, const int* __restrict__ srcs,
                                              const float* __restrict__ b2, const float* __restrict__ pw,
                                              const int* __restrict__ uidx, const int* __restrict__ jidx,
                                              int U, int B, float* __restrict__ out) {
    int wid = blockIdx.x * 4 + (threadIdx.x >> 6);
    int lane = threadIdx.x & 63;
    int g = lane >> 4, t = lane & 15;
    if (wid >= 2 * B) return;
    int isU = (wid < B);
    int b = isU ? wid : wid - B;
    int c = isU ? uidx[b] : U + jidx[b];
    float4 acc = make_float4(0.f, 0.f, 0.f, 0.f);
    int e0 = rowptr[c], e1 = rowptr[c + 1];
    for (int base0 = e0; base0 < e1; base0 += 64) {
        int j = base0 + lane;
        int s = (j < e1) ? srcs[j] : 0;
        int cnt = min(64, e1 - base0);
        int iters = (cnt + 3) >> 2;
        for (int ii = 0; ii < iters; ii++) {
            int i = ii * 4 + g;
            int si = __shfl(s, (i < cnt) ? i : 0, 64);
            if (i < cnt) {
                float4 v = *(const float4*)(hs2 + (size_t)si * D + t * 4);
                acc.x += v.x; acc.y += v.y; acc.z += v.z; acc.w += v.w;
            }
        }
    }
    acc.x += __shfl_xor(acc.x, 16, 64); acc.x += __shfl_xor(acc.x, 32, 64);
    acc.y += __shfl_xor(acc.y, 16, 64); acc.y += __shfl_xor(acc.y, 32, 64);
    acc.z += __shfl_xor(acc.z, 16, 64); acc.z += __shfl_xor(acc.z, 32, 64);
    acc.w += __shfl_xor(acc.w, 16, 64); acc.w += __shfl_xor(acc.w, 32, 64);
    float4 self = *(const float4*)(hs2 + (size_t)c * D + t * 4);
    float4 b4 = *(const float4*)(b2 + t * 4);
    float dv = dinv[c];
    float4 w4 = *(const float4*)(pw + (isU ? 0 : 64) + t * 4);
    float vx = ((acc.x + self.x) * dv + b4.x) * w4.x
             + ((acc.y + self.y) * dv + b4.y) * w4.y
             + ((acc.z + self.z) * dv + b4.z) * w4.z
             + ((acc.w + self.w) * dv + b4.w) * w4.w;
    vx += __shfl_xor(vx, 1, 64); vx += __shfl_xor(vx, 2, 64);
    vx += __shfl_xor(vx, 4, 64); vx += __shfl_xor(vx, 8, 64);
    if (lane == 0) atomicAdd(&out[b], vx);
}

// ---------------- host ----------------

extern "C" void kernel_launch(void* const* d_in, const int* in_sizes, int n_in,
                              void* d_out, int out_size, void* d_ws, size_t ws_size,
                              hipStream_t stream) {
    const int*   edge = (const int*)d_in[0];
    const int*   uidx = (const int*)d_in[1];
    const int*   jidx = (const int*)d_in[2];
    const float* xu   = (const float*)d_in[3];
    const float* xj   = (const float*)d_in[4];
    const float* W1   = (const float*)d_in[5];
    const float* b1   = (const float*)d_in[6];
    const float* W2   = (const float*)d_in[7];
    const float* b2   = (const float*)d_in[8];
    const float* pw   = (const float*)d_in[9];
    const float* pb   = (const float*)d_in[10];
    float* out = (float*)d_out;

    int E = in_sizes[0] / 2;
    int B = in_sizes[1];
    int U = in_sizes[3] / D;
    int J = in_sizes[4] / D;
    int N = U + J;
    int nbuk = (N + (1 << BSHIFT) - 1) >> BSHIFT;   // 196 for N=200000; must be <= 256
    const int* row = edge;       // sources
    const int* col = edge + E;   // targets

    char* p = (char*)d_ws;
    auto alloc = [&](size_t bytes) -> void* {
        void* q = (void*)p;
        p += (bytes + 255) / 256 * 256;
        return q;
    };
    int*   bukcnt  = (int*)alloc(256 * 4);
    int*   bb0     = (int*)alloc(257 * 4);
    int*   bbase   = (int*)alloc(256 * 4);
    int*   rowptr  = (int*)alloc((size_t)(N + 1) * 4);
    float* dinv    = (float*)alloc((size_t)N * 4);
    int*   srcs    = (int*)alloc((size_t)E * 4);
    float* h       = (float*)alloc((size_t)N * D * 4);  // aliased as ebuf before GEMMs
    float* x1      = (float*)alloc((size_t)N * D * 4);
    unsigned* ebuf = (unsigned*)h;                      // E*4 <= N*D*4 required

    hipMemsetAsync(bukcnt, 0, 256 * 4, stream);
    k_bukcnt<<<512, 256, 0, stream>>>(col, E, bukcnt);
    k_bukscan<<<1, 256, 0, stream>>>(bukcnt, nbuk, E, bb0, bbase, rowptr, N);

    // CSR build: bucketed binning (coalesced packed runs) then per-bucket LDS work
    k_bin<<<(E + T_TILE - 1) / T_TILE, 256, 0, stream>>>(row, col, E, bbase, ebuf, nbuk);
    k_csr2<<<nbuk, 256, 0, stream>>>(ebuf, bb0, N, rowptr, dinv, srcs);

    // layer 1: hs = (x @ W1) * dinv ; x1 = relu(dinv*(hs_self + sum) + b1)
    k_gemm<<<(N + 63) / 64, 256, 0, stream>>>(xu, xj, U, N, W1, dinv, h);
    k_agg<<<(N + 3) / 4, 256, 0, stream>>>(h, dinv, rowptr, srcs, b1, x1, N, 1);

    // layer 2: hs2 = (x1 @ W2) * dinv ; aggregate only at selected nodes, fused w/ predictor
    k_gemm<<<(N + 63) / 64, 256, 0, stream>>>(x1, x1, N, N, W2, dinv, h);
    k_initout<<<(B + 255) / 256, 256, 0, stream>>>(pb, out, B);
    k_pred<<<(2 * B + 3) / 4, 256, 0, stream>>>(h, dinv, rowptr, srcs, b2, pw, uidx, jidx, U, B, out);
}

// Round 5
// 419.016 us; speedup vs baseline: 1.9516x; 1.0207x over previous
//
#include <hip/hip_runtime.h>

#define D 64
#define BSHIFT 10              // nodes per bucket = 1024
#define BMASK ((1 << BSHIFT) - 1)
#define NBUK_MAX 256
#define T_TILE 6144            // edges per k_bin block (256 threads x 24)

// ---------------- per-bucket edge counts (LDS-privatized) ----------------

__global__ __launch_bounds__(256) void k_bukcnt(const int* __restrict__ col, int E,
                                                int* __restrict__ bukcnt) {
    __shared__ int h[NBUK_MAX];
    h[threadIdx.x] = 0;
    __syncthreads();
    int stride = gridDim.x * 256 * 4;
    for (int base = (blockIdx.x * 256 + threadIdx.x) * 4; base < E; base += stride) {
        if (base + 3 < E) {
            int4 c = *(const int4*)(col + base);
            atomicAdd(&h[c.x >> BSHIFT], 1);
            atomicAdd(&h[c.y >> BSHIFT], 1);
            atomicAdd(&h[c.z >> BSHIFT], 1);
            atomicAdd(&h[c.w >> BSHIFT], 1);
        } else {
            for (int k = base; k < E; k++) atomicAdd(&h[col[k] >> BSHIFT], 1);
        }
    }
    __syncthreads();
    int v = h[threadIdx.x];
    if (v) atomicAdd(&bukcnt[threadIdx.x], v);
}

// ---------------- bucket base scan (single block) ----------------

__global__ void k_bukscan(const int* __restrict__ bukcnt, int nbuk, int E,
                          int* __restrict__ bb0, int* __restrict__ bbase,
                          int* __restrict__ rowptr, int N) {
    __shared__ int sh[256];
    int tid = threadIdx.x;
    int v = (tid < nbuk) ? bukcnt[tid] : 0;
    sh[tid] = v; __syncthreads();
    for (int off = 1; off < 256; off <<= 1) {
        int u = (tid >= off) ? sh[tid - off] : 0;
        __syncthreads();
        sh[tid] += u;
        __syncthreads();
    }
    int excl = sh[tid] - v;
    if (tid < nbuk) { bb0[tid] = excl; bbase[tid] = excl; }
    if (tid == 0) { bb0[nbuk] = E; rowptr[N] = E; }
}

// ---------------- bucket binning with LDS reorder (per-wave hist/cursors) ----------------
// packed entry: (c & BMASK) << 18 | r   — requires N <= 2^18 (N=200000 here)

__global__ __launch_bounds__(256) void k_bin(const int* __restrict__ row, const int* __restrict__ col,
                                             int E, int* __restrict__ bbase,
                                             unsigned* __restrict__ ebuf, int nbuk) {
    __shared__ int hist4[4][NBUK_MAX];     // 4 KB
    __shared__ int scan[NBUK_MAX];
    __shared__ int sexcl[NBUK_MAX];
    __shared__ int cur4[4][NBUK_MAX];      // 4 KB
    __shared__ int gbase[NBUK_MAX];
    __shared__ unsigned stage[T_TILE];     // 24 KB
    __shared__ unsigned char sbuk[T_TILE]; // 6 KB
    int tid = threadIdx.x;
    int w = tid >> 6;
    int tile0 = blockIdx.x * T_TILE;
    int cnt = min(T_TILE, E - tile0);

#pragma unroll
    for (int q = 0; q < 4; q++) hist4[q][tid] = 0;
    __syncthreads();
    for (int i = tid; i < cnt; i += 256)
        atomicAdd(&hist4[w][col[tile0 + i] >> BSHIFT], 1);
    __syncthreads();

    int h0 = hist4[0][tid], h1 = hist4[1][tid], h2 = hist4[2][tid], h3 = hist4[3][tid];
    int v = h0 + h1 + h2 + h3;
    scan[tid] = v; __syncthreads();
    for (int off = 1; off < 256; off <<= 1) {
        int u = (tid >= off) ? scan[tid - off] : 0;
        __syncthreads();
        scan[tid] += u;
        __syncthreads();
    }
    int excl = scan[tid] - v;
    sexcl[tid] = excl;
    cur4[0][tid] = excl;
    cur4[1][tid] = excl + h0;
    cur4[2][tid] = excl + h0 + h1;
    cur4[3][tid] = excl + h0 + h1 + h2;
    gbase[tid] = (v > 0 && tid < nbuk) ? atomicAdd(&bbase[tid], v) : 0;
    __syncthreads();

    for (int i = tid; i < cnt; i += 256) {
        int r = row[tile0 + i];
        int c = col[tile0 + i];
        int b = c >> BSHIFT;
        int p = atomicAdd(&cur4[w][b], 1);
        stage[p] = ((unsigned)(c & BMASK) << 18) | (unsigned)r;
        sbuk[p] = (unsigned char)b;
    }
    __syncthreads();

    for (int i = tid; i < cnt; i += 256) {
        int b = sbuk[i];
        int gpos = gbase[b] + (i - sexcl[b]);
        ebuf[gpos] = stage[i];
    }
}

// ---------------- per-bucket degree count + rowptr + dinv + CSR scatter ----------------

__global__ __launch_bounds__(256) void k_csr2(const unsigned* __restrict__ ebuf,
                                              const int* __restrict__ bb0, int N,
                                              int* __restrict__ rowptr, float* __restrict__ dinv,
                                              int* __restrict__ srcs) {
    __shared__ int lcnt[1 << BSHIFT];  // 4 KB
    __shared__ int lcur[1 << BSHIFT];  // 4 KB
    __shared__ int ssum[256];
    int tid = threadIdx.x;
    int c0 = blockIdx.x << BSHIFT;
    int nn = min(1 << BSHIFT, N - c0);
    int e0 = bb0[blockIdx.x], e1 = bb0[blockIdx.x + 1];

    for (int i = tid; i < (1 << BSHIFT); i += 256) lcnt[i] = 0;
    __syncthreads();
    for (int j = e0 + tid; j < e1; j += 256)
        atomicAdd(&lcnt[ebuf[j] >> 18], 1);
    __syncthreads();

    int c[4]; int s = 0;
#pragma unroll
    for (int i = 0; i < 4; i++) { c[i] = lcnt[tid * 4 + i]; s += c[i]; }
    ssum[tid] = s; __syncthreads();
    for (int off = 1; off < 256; off <<= 1) {
        int u = (tid >= off) ? ssum[tid - off] : 0;
        __syncthreads();
        ssum[tid] += u;
        __syncthreads();
    }
    int run = ssum[tid] - s;  // exclusive
#pragma unroll
    for (int i = 0; i < 4; i++) {
        int idx = tid * 4 + i;
        lcur[idx] = run;
        if (idx < nn) {
            rowptr[c0 + idx] = e0 + run;
            dinv[c0 + idx] = rsqrtf((float)(c[i] + 1));  // +1 self loop
        }
        run += c[i];
    }
    __syncthreads();

    for (int j = e0 + tid; j < e1; j += 256) {
        unsigned pk = ebuf[j];
        int p = atomicAdd(&lcur[pk >> 18], 1);
        srcs[e0 + p] = (int)(pk & 0x3ffffu);
    }
}

// ---------------- dense: h[n][c] = dinv[n] * sum_k x[n][k] * W[k][c] ----------------

__global__ __launch_bounds__(256) void k_gemm(const float* __restrict__ xu, const float* __restrict__ xj,
                                              int U, int N, const float* __restrict__ W,
                                              const float* __restrict__ dinv, float* __restrict__ h) {
    __shared__ float Ws[64 * 64];
    __shared__ float Xs[64 * 68];
    int tid = threadIdx.x;
#pragma unroll
    for (int i = 0; i < 16; i++) Ws[tid + i * 256] = W[tid + i * 256];
    int n0 = blockIdx.x * 64;
#pragma unroll
    for (int i = 0; i < 4; i++) {
        int e4 = tid + i * 256;
        int nl = e4 >> 4, k4 = e4 & 15;
        int nn = n0 + nl;
        float4 v = make_float4(0.f, 0.f, 0.f, 0.f);
        if (nn < N) {
            const float* src = (nn < U) ? (xu + (size_t)nn * D) : (xj + (size_t)(nn - U) * D);
            v = *(const float4*)(src + k4 * 4);
        }
        *(float4*)(&Xs[nl * 68 + k4 * 4]) = v;
    }
    __syncthreads();
    int tx = tid & 15, ty = tid >> 4;
    float acc[4][4];
#pragma unroll
    for (int r = 0; r < 4; r++)
#pragma unroll
        for (int c = 0; c < 4; c++) acc[r][c] = 0.f;
#pragma unroll 16
    for (int k = 0; k < 64; k++) {
        float xv[4], wv[4];
#pragma unroll
        for (int r = 0; r < 4; r++) xv[r] = Xs[(ty * 4 + r) * 68 + k];
#pragma unroll
        for (int c = 0; c < 4; c++) wv[c] = Ws[k * 64 + tx * 4 + c];
#pragma unroll
        for (int r = 0; r < 4; r++)
#pragma unroll
            for (int c = 0; c < 4; c++) acc[r][c] += xv[r] * wv[c];
    }
#pragma unroll
    for (int r = 0; r < 4; r++) {
        int nn = n0 + ty * 4 + r;
        if (nn < N) {
            float sc = dinv[nn];
            float4 o = make_float4(acc[r][0] * sc, acc[r][1] * sc, acc[r][2] * sc, acc[r][3] * sc);
            *(float4*)(&h[(size_t)nn * D + tx * 4]) = o;
        }
    }
}

// ---------------- pull aggregation (full N), 16-edge-unrolled float4 gathers ----------------
// wave = 1 node; lane = g*16+t; group g handles slots {ii+g, ii+4+g, ii+8+g, ii+12+g}
// per iteration: 4 independent float4 loads in flight per lane.

__global__ __launch_bounds__(256) void k_agg(const float* __restrict__ hs, const float* __restrict__ dinv,
                                             const int* __restrict__ rowptr, const int* __restrict__ srcs,
                                             const float* __restrict__ bias, float* __restrict__ xout,
                                             int N, int do_relu) {
    int node = blockIdx.x * 4 + (threadIdx.x >> 6);
    int lane = threadIdx.x & 63;
    int g = lane >> 4, t = lane & 15;
    if (node >= N) return;
    const float* hp = hs + t * 4;
    float4 acc = make_float4(0.f, 0.f, 0.f, 0.f);
    int e0 = rowptr[node], e1 = rowptr[node + 1];
    for (int base0 = e0; base0 < e1; base0 += 64) {
        int j = base0 + lane;
        int s = (j < e1) ? srcs[j] : 0;
        int cnt = min(64, e1 - base0);
        for (int ii = 0; ii < cnt; ii += 16) {
            int i0 = ii + g, i1 = ii + g + 4, i2 = ii + g + 8, i3 = ii + g + 12;
            int s0 = __shfl(s, (i0 < cnt) ? i0 : 0, 64);
            int s1 = __shfl(s, (i1 < cnt) ? i1 : 0, 64);
            int s2 = __shfl(s, (i2 < cnt) ? i2 : 0, 64);
            int s3 = __shfl(s, (i3 < cnt) ? i3 : 0, 64);
            float4 v0 = *(const float4*)(hp + (size_t)s0 * D);
            float4 v1 = *(const float4*)(hp + (size_t)s1 * D);
            float4 v2 = *(const float4*)(hp + (size_t)s2 * D);
            float4 v3 = *(const float4*)(hp + (size_t)s3 * D);
            if (i0 < cnt) { acc.x += v0.x; acc.y += v0.y; acc.z += v0.z; acc.w += v0.w; }
            if (i1 < cnt) { acc.x += v1.x; acc.y += v1.y; acc.z += v1.z; acc.w += v1.w; }
            if (i2 < cnt) { acc.x += v2.x; acc.y += v2.y; acc.z += v2.z; acc.w += v2.w; }
            if (i3 < cnt) { acc.x += v3.x; acc.y += v3.y; acc.z += v3.z; acc.w += v3.w; }
        }
    }
    acc.x += __shfl_xor(acc.x, 16, 64); acc.x += __shfl_xor(acc.x, 32, 64);
    acc.y += __shfl_xor(acc.y, 16, 64); acc.y += __shfl_xor(acc.y, 32, 64);
    acc.z += __shfl_xor(acc.z, 16, 64); acc.z += __shfl_xor(acc.z, 32, 64);
    acc.w += __shfl_xor(acc.w, 16, 64); acc.w += __shfl_xor(acc.w, 32, 64);
    float4 self = *(const float4*)(hs + (size_t)node * D + t * 4);
    float4 b4 = *(const float4*)(bias + t * 4);
    float dv = dinv[node];
    float4 o;
    o.x = (acc.x + self.x) * dv + b4.x;
    o.y = (acc.y + self.y) * dv + b4.y;
    o.z = (acc.z + self.z) * dv + b4.z;
    o.w = (acc.w + self.w) * dv + b4.w;
    if (do_relu) {
        o.x = fmaxf(o.x, 0.f); o.y = fmaxf(o.y, 0.f);
        o.z = fmaxf(o.z, 0.f); o.w = fmaxf(o.w, 0.f);
    }
    if (g == 0) *(float4*)(xout + (size_t)node * D + t * 4) = o;
}

// ---------------- fused layer-2 selected-node aggregation + prediction ----------------

__global__ void k_initout(const float* __restrict__ pb, float* __restrict__ out, int B) {
    int i = blockIdx.x * 256 + threadIdx.x;
    if (i < B) out[i] = pb[0];
}

__global__ __launch_bounds__(256) void k_pred(const float* __restrict__ hs2, const float* __restrict__ dinv,
                                              const int* __restrict__ rowptr, const int* __restrict__ srcs,
                                              const float* __restrict__ b2, const float* __restrict__ pw,
                                              const int* __restrict__ uidx, const int* __restrict__ jidx,
                                              int U, int B, float* __restrict__ out) {
    int wid = blockIdx.x * 4 + (threadIdx.x >> 6);
    int lane = threadIdx.x & 63;
    int g = lane >> 4, t = lane & 15;
    if (wid >= 2 * B) return;
    int isU = (wid < B);
    int b = isU ? wid : wid - B;
    int c = isU ? uidx[b] : U + jidx[b];
    const float* hp = hs2 + t * 4;
    float4 acc = make_float4(0.f, 0.f, 0.f, 0.f);
    int e0 = rowptr[c], e1 = rowptr[c + 1];
    for (int base0 = e0; base0 < e1; base0 += 64) {
        int j = base0 + lane;
        int s = (j < e1) ? srcs[j] : 0;
        int cnt = min(64, e1 - base0);
        for (int ii = 0; ii < cnt; ii += 16) {
            int i0 = ii + g, i1 = ii + g + 4, i2 = ii + g + 8, i3 = ii + g + 12;
            int s0 = __shfl(s, (i0 < cnt) ? i0 : 0, 64);
            int s1 = __shfl(s, (i1 < cnt) ? i1 : 0, 64);
            int s2 = __shfl(s, (i2 < cnt) ? i2 : 0, 64);
            int s3 = __shfl(s, (i3 < cnt) ? i3 : 0, 64);
            float4 v0 = *(const float4*)(hp + (size_t)s0 * D);
            float4 v1 = *(const float4*)(hp + (size_t)s1 * D);
            float4 v2 = *(const float4*)(hp + (size_t)s2 * D);
            float4 v3 = *(const float4*)(hp + (size_t)s3 * D);
            if (i0 < cnt) { acc.x += v0.x; acc.y += v0.y; acc.z += v0.z; acc.w += v0.w; }
            if (i1 < cnt) { acc.x += v1.x; acc.y += v1.y; acc.z += v1.z; acc.w += v1.w; }
            if (i2 < cnt) { acc.x += v2.x; acc.y += v2.y; acc.z += v2.z; acc.w += v2.w; }
            if (i3 < cnt) { acc.x += v3.x; acc.y += v3.y; acc.z += v3.z; acc.w += v3.w; }
        }
    }
    acc.x += __shfl_xor(acc.x, 16, 64); acc.x += __shfl_xor(acc.x, 32, 64);
    acc.y += __shfl_xor(acc.y, 16, 64); acc.y += __shfl_xor(acc.y, 32, 64);
    acc.z += __shfl_xor(acc.z, 16, 64); acc.z += __shfl_xor(acc.z, 32, 64);
    acc.w += __shfl_xor(acc.w, 16, 64); acc.w += __shfl_xor(acc.w, 32, 64);
    float4 self = *(const float4*)(hs2 + (size_t)c * D + t * 4);
    float4 b4 = *(const float4*)(b2 + t * 4);
    float dv = dinv[c];
    float4 w4 = *(const float4*)(pw + (isU ? 0 : 64) + t * 4);
    float vx = ((acc.x + self.x) * dv + b4.x) * w4.x
             + ((acc.y + self.y) * dv + b4.y) * w4.y
             + ((acc.z + self.z) * dv + b4.z) * w4.z
             + ((acc.w + self.w) * dv + b4.w) * w4.w;
    vx += __shfl_xor(vx, 1, 64); vx += __shfl_xor(vx, 2, 64);
    vx += __shfl_xor(vx, 4, 64); vx += __shfl_xor(vx, 8, 64);
    if (lane == 0) atomicAdd(&out[b], vx);
}

// ---------------- host ----------------

extern "C" void kernel_launch(void* const* d_in, const int* in_sizes, int n_in,
                              void* d_out, int out_size, void* d_ws, size_t ws_size,
                              hipStream_t stream) {
    const int*   edge = (const int*)d_in[0];
    const int*   uidx = (const int*)d_in[1];
    const int*   jidx = (const int*)d_in[2];
    const float* xu   = (const float*)d_in[3];
    const float* xj   = (const float*)d_in[4];
    const float* W1   = (const float*)d_in[5];
    const float* b1   = (const float*)d_in[6];
    const float* W2   = (const float*)d_in[7];
    const float* b2   = (const float*)d_in[8];
    const float* pw   = (const float*)d_in[9];
    const float* pb   = (const float*)d_in[10];
    float* out = (float*)d_out;

    int E = in_sizes[0] / 2;
    int B = in_sizes[1];
    int U = in_sizes[3] / D;
    int J = in_sizes[4] / D;
    int N = U + J;
    int nbuk = (N + (1 << BSHIFT) - 1) >> BSHIFT;   // 196 for N=200000; must be <= 256
    const int* row = edge;       // sources
    const int* col = edge + E;   // targets

    char* p = (char*)d_ws;
    auto alloc = [&](size_t bytes) -> void* {
        void* q = (void*)p;
        p += (bytes + 255) / 256 * 256;
        return q;
    };
    int*   bukcnt  = (int*)alloc(256 * 4);
    int*   bb0     = (int*)alloc(257 * 4);
    int*   bbase   = (int*)alloc(256 * 4);
    int*   rowptr  = (int*)alloc((size_t)(N + 1) * 4);
    float* dinv    = (float*)alloc((size_t)N * 4);
    int*   srcs    = (int*)alloc((size_t)E * 4);
    float* h       = (float*)alloc((size_t)N * D * 4);  // aliased as ebuf before GEMMs
    float* x1      = (float*)alloc((size_t)N * D * 4);
    unsigned* ebuf = (unsigned*)h;                      // E*4 <= N*D*4 required

    hipMemsetAsync(bukcnt, 0, 256 * 4, stream);
    k_bukcnt<<<512, 256, 0, stream>>>(col, E, bukcnt);
    k_bukscan<<<1, 256, 0, stream>>>(bukcnt, nbuk, E, bb0, bbase, rowptr, N);

    // CSR build: bucketed binning (coalesced packed runs) then per-bucket LDS work
    k_bin<<<(E + T_TILE - 1) / T_TILE, 256, 0, stream>>>(row, col, E, bbase, ebuf, nbuk);
    k_csr2<<<nbuk, 256, 0, stream>>>(ebuf, bb0, N, rowptr, dinv, srcs);

    // layer 1: hs = (x @ W1) * dinv ; x1 = relu(dinv*(hs_self + sum) + b1)
    k_gemm<<<(N + 63) / 64, 256, 0, stream>>>(xu, xj, U, N, W1, dinv, h);
    k_agg<<<(N + 3) / 4, 256, 0, stream>>>(h, dinv, rowptr, srcs, b1, x1, N, 1);

    // layer 2: hs2 = (x1 @ W2) * dinv ; aggregate only at selected nodes, fused w/ predictor
    k_gemm<<<(N + 63) / 64, 256, 0, stream>>>(x1, x1, N, N, W2, dinv, h);
    k_initout<<<(B + 255) / 256, 256, 0, stream>>>(pb, out, B);
    k_pred<<<(2 * B + 3) / 4, 256, 0, stream>>>(h, dinv, rowptr, srcs, b2, pw, uidx, jidx, U, B, out);
}

// Round 6
// 366.648 us; speedup vs baseline: 2.2303x; 1.1428x over previous
//
#include <hip/hip_runtime.h>
#include <hip/hip_fp16.h>

#define D 64
#define BSHIFT 10              // nodes per bucket = 1024
#define BMASK ((1 << BSHIFT) - 1)
#define NBUK_MAX 256
#define T_TILE 6144            // edges per k_bin block (256 threads x 24)

// inclusive wave scan (64 lanes)
__device__ __forceinline__ int wave_iscan(int v, int lane) {
#pragma unroll
    for (int off = 1; off < 64; off <<= 1) {
        int u = __shfl_up(v, off, 64);
        if (lane >= off) v += u;
    }
    return v;
}

// block-wide (256 thr) exclusive scan of per-thread value v; returns exclusive prefix
__device__ __forceinline__ int block_escan(int v, int tid, int* wtot /*>=4 ints LDS*/) {
    int lane = tid & 63, w = tid >> 6;
    int inc = wave_iscan(v, lane);
    if (lane == 63) wtot[w] = inc;
    __syncthreads();
    int addv = 0;
#pragma unroll
    for (int q = 0; q < 4; q++) addv += (q < w) ? wtot[q] : 0;
    return inc - v + addv;
}

__device__ __forceinline__ float4 h4_to_f4(uint2 u) {
    __half2 a = *(__half2*)&u.x, b = *(__half2*)&u.y;
    float2 fa = __half22float2(a), fb = __half22float2(b);
    return make_float4(fa.x, fa.y, fb.x, fb.y);
}

// ---------------- per-bucket edge counts (LDS-privatized) ----------------

__global__ __launch_bounds__(256) void k_bukcnt(const int* __restrict__ col, int E,
                                                int* __restrict__ bukcnt) {
    __shared__ int h[NBUK_MAX];
    h[threadIdx.x] = 0;
    __syncthreads();
    int stride = gridDim.x * 256 * 4;
    for (int base = (blockIdx.x * 256 + threadIdx.x) * 4; base < E; base += stride) {
        if (base + 3 < E) {
            int4 c = *(const int4*)(col + base);
            atomicAdd(&h[c.x >> BSHIFT], 1);
            atomicAdd(&h[c.y >> BSHIFT], 1);
            atomicAdd(&h[c.z >> BSHIFT], 1);
            atomicAdd(&h[c.w >> BSHIFT], 1);
        } else {
            for (int k = base; k < E; k++) atomicAdd(&h[col[k] >> BSHIFT], 1);
        }
    }
    __syncthreads();
    int v = h[threadIdx.x];
    if (v) atomicAdd(&bukcnt[threadIdx.x], v);
}

// ---------------- bucket base scan (single block) ----------------

__global__ void k_bukscan(const int* __restrict__ bukcnt, int nbuk, int E,
                          int* __restrict__ bb0, int* __restrict__ bbase,
                          int* __restrict__ rowptr, int N) {
    __shared__ int wtot[4];
    int tid = threadIdx.x;
    int v = (tid < nbuk) ? bukcnt[tid] : 0;
    int excl = block_escan(v, tid, wtot);
    if (tid < nbuk) { bb0[tid] = excl; bbase[tid] = excl; }
    if (tid == 0) { bb0[nbuk] = E; rowptr[N] = E; }
}

// ---------------- bucket binning with LDS reorder (per-wave hist/cursors) ----------------
// packed entry: (c & BMASK) << 18 | r   — requires N <= 2^18 (N=200000 here)

__global__ __launch_bounds__(256) void k_bin(const int* __restrict__ row, const int* __restrict__ col,
                                             int E, int* __restrict__ bbase,
                                             unsigned* __restrict__ ebuf, int nbuk) {
    __shared__ int hist4[4][NBUK_MAX];     // 4 KB
    __shared__ int sexcl[NBUK_MAX];
    __shared__ int cur4[4][NBUK_MAX];      // 4 KB
    __shared__ int gbase[NBUK_MAX];
    __shared__ int wtot[4];
    __shared__ unsigned stage[T_TILE];     // 24 KB
    __shared__ unsigned char sbuk[T_TILE]; // 6 KB
    int tid = threadIdx.x;
    int w = tid >> 6;
    int tile0 = blockIdx.x * T_TILE;
    int cnt = min(T_TILE, E - tile0);

#pragma unroll
    for (int q = 0; q < 4; q++) hist4[q][tid] = 0;
    __syncthreads();
    for (int i = tid; i < cnt; i += 256)
        atomicAdd(&hist4[w][col[tile0 + i] >> BSHIFT], 1);
    __syncthreads();

    int h0 = hist4[0][tid], h1 = hist4[1][tid], h2 = hist4[2][tid], h3 = hist4[3][tid];
    int v = h0 + h1 + h2 + h3;
    int excl = block_escan(v, tid, wtot);
    sexcl[tid] = excl;
    cur4[0][tid] = excl;
    cur4[1][tid] = excl + h0;
    cur4[2][tid] = excl + h0 + h1;
    cur4[3][tid] = excl + h0 + h1 + h2;
    gbase[tid] = (v > 0 && tid < nbuk) ? atomicAdd(&bbase[tid], v) : 0;
    __syncthreads();

    for (int i = tid; i < cnt; i += 256) {
        int r = row[tile0 + i];
        int c = col[tile0 + i];
        int b = c >> BSHIFT;
        int p = atomicAdd(&cur4[w][b], 1);
        stage[p] = ((unsigned)(c & BMASK) << 18) | (unsigned)r;
        sbuk[p] = (unsigned char)b;
    }
    __syncthreads();

    for (int i = tid; i < cnt; i += 256) {
        int b = sbuk[i];
        int gpos = gbase[b] + (i - sexcl[b]);
        ebuf[gpos] = stage[i];
    }
}

// ---------------- per-bucket degree count + rowptr + dinv + CSR scatter ----------------

__global__ __launch_bounds__(256) void k_csr2(const unsigned* __restrict__ ebuf,
                                              const int* __restrict__ bb0, int N,
                                              int* __restrict__ rowptr, float* __restrict__ dinv,
                                              int* __restrict__ srcs) {
    __shared__ int lcnt[1 << BSHIFT];  // 4 KB
    __shared__ int lcur[1 << BSHIFT];  // 4 KB
    __shared__ int wtot[4];
    int tid = threadIdx.x;
    int c0 = blockIdx.x << BSHIFT;
    int nn = min(1 << BSHIFT, N - c0);
    int e0 = bb0[blockIdx.x], e1 = bb0[blockIdx.x + 1];

    for (int i = tid; i < (1 << BSHIFT); i += 256) lcnt[i] = 0;
    __syncthreads();
    for (int j = e0 + tid; j < e1; j += 256)
        atomicAdd(&lcnt[ebuf[j] >> 18], 1);
    __syncthreads();

    int c[4]; int s = 0;
#pragma unroll
    for (int i = 0; i < 4; i++) { c[i] = lcnt[tid * 4 + i]; s += c[i]; }
    int run = block_escan(s, tid, wtot);
    __syncthreads();  // lcnt reads done before lcur overwrite ordering below is safe (distinct arrays) — barrier for wtot reuse safety
#pragma unroll
    for (int i = 0; i < 4; i++) {
        int idx = tid * 4 + i;
        lcur[idx] = run;
        if (idx < nn) {
            rowptr[c0 + idx] = e0 + run;
            dinv[c0 + idx] = rsqrtf((float)(c[i] + 1));  // +1 self loop
        }
        run += c[i];
    }
    __syncthreads();

    for (int j = e0 + tid; j < e1; j += 256) {
        unsigned pk = ebuf[j];
        int p = atomicAdd(&lcur[pk >> 18], 1);
        srcs[e0 + p] = (int)(pk & 0x3ffffu);
    }
}

// ---------------- dense: h[n][c] = fp16( dinv[n] * sum_k x[n][k] * W[k][c] ) ----------------
// IN_HALF=0: inputs fp32 (xu/xj split); IN_HALF=1: single fp16 input (xu==xj)

template<int IN_HALF>
__global__ __launch_bounds__(256) void k_gemm(const void* __restrict__ xu_, const void* __restrict__ xj_,
                                              int U, int N, const float* __restrict__ W,
                                              const float* __restrict__ dinv, __half* __restrict__ h) {
    __shared__ float Ws[64 * 64];
    __shared__ float Xs[64 * 68];
    int tid = threadIdx.x;
#pragma unroll
    for (int i = 0; i < 16; i++) Ws[tid + i * 256] = W[tid + i * 256];
    int n0 = blockIdx.x * 64;
#pragma unroll
    for (int i = 0; i < 4; i++) {
        int e4 = tid + i * 256;
        int nl = e4 >> 4, k4 = e4 & 15;
        int nn = n0 + nl;
        float4 v = make_float4(0.f, 0.f, 0.f, 0.f);
        if (nn < N) {
            if (IN_HALF) {
                const __half* src = (const __half*)xu_ + (size_t)nn * D;
                v = h4_to_f4(*(const uint2*)(src + k4 * 4));
            } else {
                const float* src = (nn < U) ? ((const float*)xu_ + (size_t)nn * D)
                                            : ((const float*)xj_ + (size_t)(nn - U) * D);
                v = *(const float4*)(src + k4 * 4);
            }
        }
        *(float4*)(&Xs[nl * 68 + k4 * 4]) = v;
    }
    __syncthreads();
    int tx = tid & 15, ty = tid >> 4;
    float acc[4][4];
#pragma unroll
    for (int r = 0; r < 4; r++)
#pragma unroll
        for (int c = 0; c < 4; c++) acc[r][c] = 0.f;
#pragma unroll 16
    for (int k = 0; k < 64; k++) {
        float xv[4], wv[4];
#pragma unroll
        for (int r = 0; r < 4; r++) xv[r] = Xs[(ty * 4 + r) * 68 + k];
#pragma unroll
        for (int c = 0; c < 4; c++) wv[c] = Ws[k * 64 + tx * 4 + c];
#pragma unroll
        for (int r = 0; r < 4; r++)
#pragma unroll
            for (int c = 0; c < 4; c++) acc[r][c] += xv[r] * wv[c];
    }
#pragma unroll
    for (int r = 0; r < 4; r++) {
        int nn = n0 + ty * 4 + r;
        if (nn < N) {
            float sc = dinv[nn];
            __half2 p0 = __floats2half2_rn(acc[r][0] * sc, acc[r][1] * sc);
            __half2 p1 = __floats2half2_rn(acc[r][2] * sc, acc[r][3] * sc);
            uint2 st; st.x = *(unsigned*)&p0; st.y = *(unsigned*)&p1;
            *(uint2*)(h + (size_t)nn * D + tx * 4) = st;
        }
    }
}

// ---------------- pull aggregation (full N), 16-edge-unrolled fp16 gathers ----------------
// wave = 1 node; lane = g*16+t; group g handles slots {ii+g, ii+4+g, ii+8+g, ii+12+g}
// lane t covers features [4t,4t+4): one dwordx2 (8 B) per edge-slot.

__global__ __launch_bounds__(256) void k_agg(const __half* __restrict__ hs, const float* __restrict__ dinv,
                                             const int* __restrict__ rowptr, const int* __restrict__ srcs,
                                             const float* __restrict__ bias, __half* __restrict__ xout,
                                             int N, int do_relu) {
    int node = blockIdx.x * 4 + (threadIdx.x >> 6);
    int lane = threadIdx.x & 63;
    int g = lane >> 4, t = lane & 15;
    if (node >= N) return;
    const __half* hp = hs + t * 4;
    float4 acc = make_float4(0.f, 0.f, 0.f, 0.f);
    int e0 = rowptr[node], e1 = rowptr[node + 1];
    for (int base0 = e0; base0 < e1; base0 += 64) {
        int j = base0 + lane;
        int s = (j < e1) ? srcs[j] : 0;
        int cnt = min(64, e1 - base0);
        for (int ii = 0; ii < cnt; ii += 16) {
            int i0 = ii + g, i1 = ii + g + 4, i2 = ii + g + 8, i3 = ii + g + 12;
            int s0 = __shfl(s, (i0 < cnt) ? i0 : 0, 64);
            int s1 = __shfl(s, (i1 < cnt) ? i1 : 0, 64);
            int s2 = __shfl(s, (i2 < cnt) ? i2 : 0, 64);
            int s3 = __shfl(s, (i3 < cnt) ? i3 : 0, 64);
            uint2 u0 = *(const uint2*)(hp + (size_t)s0 * D);
            uint2 u1 = *(const uint2*)(hp + (size_t)s1 * D);
            uint2 u2 = *(const uint2*)(hp + (size_t)s2 * D);
            uint2 u3 = *(const uint2*)(hp + (size_t)s3 * D);
            float4 v0 = h4_to_f4(u0), v1 = h4_to_f4(u1), v2 = h4_to_f4(u2), v3 = h4_to_f4(u3);
            if (i0 < cnt) { acc.x += v0.x; acc.y += v0.y; acc.z += v0.z; acc.w += v0.w; }
            if (i1 < cnt) { acc.x += v1.x; acc.y += v1.y; acc.z += v1.z; acc.w += v1.w; }
            if (i2 < cnt) { acc.x += v2.x; acc.y += v2.y; acc.z += v2.z; acc.w += v2.w; }
            if (i3 < cnt) { acc.x += v3.x; acc.y += v3.y; acc.z += v3.z; acc.w += v3.w; }
        }
    }
    acc.x += __shfl_xor(acc.x, 16, 64); acc.x += __shfl_xor(acc.x, 32, 64);
    acc.y += __shfl_xor(acc.y, 16, 64); acc.y += __shfl_xor(acc.y, 32, 64);
    acc.z += __shfl_xor(acc.z, 16, 64); acc.z += __shfl_xor(acc.z, 32, 64);
    acc.w += __shfl_xor(acc.w, 16, 64); acc.w += __shfl_xor(acc.w, 32, 64);
    float4 self = h4_to_f4(*(const uint2*)(hs + (size_t)node * D + t * 4));
    float4 b4 = *(const float4*)(bias + t * 4);
    float dv = dinv[node];
    float4 o;
    o.x = (acc.x + self.x) * dv + b4.x;
    o.y = (acc.y + self.y) * dv + b4.y;
    o.z = (acc.z + self.z) * dv + b4.z;
    o.w = (acc.w + self.w) * dv + b4.w;
    if (do_relu) {
        o.x = fmaxf(o.x, 0.f); o.y = fmaxf(o.y, 0.f);
        o.z = fmaxf(o.z, 0.f); o.w = fmaxf(o.w, 0.f);
    }
    if (g == 0) {
        __half2 p0 = __floats2half2_rn(o.x, o.y);
        __half2 p1 = __floats2half2_rn(o.z, o.w);
        uint2 st; st.x = *(unsigned*)&p0; st.y = *(unsigned*)&p1;
        *(uint2*)(xout + (size_t)node * D + t * 4) = st;
    }
}

// ---------------- fused layer-2 selected-node aggregation + prediction ----------------

__global__ void k_initout(const float* __restrict__ pb, float* __restrict__ out, int B) {
    int i = blockIdx.x * 256 + threadIdx.x;
    if (i < B) out[i] = pb[0];
}

__global__ __launch_bounds__(256) void k_pred(const __half* __restrict__ hs2, const float* __restrict__ dinv,
                                              const int* __restrict__ rowptr, const int* __restrict__ srcs,
                                              const float* __restrict__ b2, const float* __restrict__ pw,
                                              const int* __restrict__ uidx, const int* __restrict__ jidx,
                                              int U, int B, float* __restrict__ out) {
    int wid = blockIdx.x * 4 + (threadIdx.x >> 6);
    int lane = threadIdx.x & 63;
    int g = lane >> 4, t = lane & 15;
    if (wid >= 2 * B) return;
    int isU = (wid < B);
    int b = isU ? wid : wid - B;
    int c = isU ? uidx[b] : U + jidx[b];
    const __half* hp = hs2 + t * 4;
    float4 acc = make_float4(0.f, 0.f, 0.f, 0.f);
    int e0 = rowptr[c], e1 = rowptr[c + 1];
    for (int base0 = e0; base0 < e1; base0 += 64) {
        int j = base0 + lane;
        int s = (j < e1) ? srcs[j] : 0;
        int cnt = min(64, e1 - base0);
        for (int ii = 0; ii < cnt; ii += 16) {
            int i0 = ii + g, i1 = ii + g + 4, i2 = ii + g + 8, i3 = ii + g + 12;
            int s0 = __shfl(s, (i0 < cnt) ? i0 : 0, 64);
            int s1 = __shfl(s, (i1 < cnt) ? i1 : 0, 64);
            int s2 = __shfl(s, (i2 < cnt) ? i2 : 0, 64);
            int s3 = __shfl(s, (i3 < cnt) ? i3 : 0, 64);
            uint2 u0 = *(const uint2*)(hp + (size_t)s0 * D);
            uint2 u1 = *(const uint2*)(hp + (size_t)s1 * D);
            uint2 u2 = *(const uint2*)(hp + (size_t)s2 * D);
            uint2 u3 = *(const uint2*)(hp + (size_t)s3 * D);
            float4 v0 = h4_to_f4(u0), v1 = h4_to_f4(u1), v2 = h4_to_f4(u2), v3 = h4_to_f4(u3);
            if (i0 < cnt) { acc.x += v0.x; acc.y += v0.y; acc.z += v0.z; acc.w += v0.w; }
            if (i1 < cnt) { acc.x += v1.x; acc.y += v1.y; acc.z += v1.z; acc.w += v1.w; }
            if (i2 < cnt) { acc.x += v2.x; acc.y += v2.y; acc.z += v2.z; acc.w += v2.w; }
            if (i3 < cnt) { acc.x += v3.x; acc.y += v3.y; acc.z += v3.z; acc.w += v3.w; }
        }
    }
    acc.x += __shfl_xor(acc.x, 16, 64); acc.x += __shfl_xor(acc.x, 32, 64);
    acc.y += __shfl_xor(acc.y, 16, 64); acc.y += __shfl_xor(acc.y, 32, 64);
    acc.z += __shfl_xor(acc.z, 16, 64); acc.z += __shfl_xor(acc.z, 32, 64);
    acc.w += __shfl_xor(acc.w, 16, 64); acc.w += __shfl_xor(acc.w, 32, 64);
    float4 self = h4_to_f4(*(const uint2*)(hs2 + (size_t)c * D + t * 4));
    float4 b4 = *(const float4*)(b2 + t * 4);
    float dv = dinv[c];
    float4 w4 = *(const float4*)(pw + (isU ? 0 : 64) + t * 4);
    float vx = ((acc.x + self.x) * dv + b4.x) * w4.x
             + ((acc.y + self.y) * dv + b4.y) * w4.y
             + ((acc.z + self.z) * dv + b4.z) * w4.z
             + ((acc.w + self.w) * dv + b4.w) * w4.w;
    vx += __shfl_xor(vx, 1, 64); vx += __shfl_xor(vx, 2, 64);
    vx += __shfl_xor(vx, 4, 64); vx += __shfl_xor(vx, 8, 64);
    if (lane == 0) atomicAdd(&out[b], vx);
}

// ---------------- host ----------------

extern "C" void kernel_launch(void* const* d_in, const int* in_sizes, int n_in,
                              void* d_out, int out_size, void* d_ws, size_t ws_size,
                              hipStream_t stream) {
    const int*   edge = (const int*)d_in[0];
    const int*   uidx = (const int*)d_in[1];
    const int*   jidx = (const int*)d_in[2];
    const float* xu   = (const float*)d_in[3];
    const float* xj   = (const float*)d_in[4];
    const float* W1   = (const float*)d_in[5];
    const float* b1   = (const float*)d_in[6];
    const float* W2   = (const float*)d_in[7];
    const float* b2   = (const float*)d_in[8];
    const float* pw   = (const float*)d_in[9];
    const float* pb   = (const float*)d_in[10];
    float* out = (float*)d_out;

    int E = in_sizes[0] / 2;
    int B = in_sizes[1];
    int U = in_sizes[3] / D;
    int J = in_sizes[4] / D;
    int N = U + J;
    int nbuk = (N + (1 << BSHIFT) - 1) >> BSHIFT;   // 196 for N=200000; must be <= 256
    const int* row = edge;       // sources
    const int* col = edge + E;   // targets

    char* p = (char*)d_ws;
    auto alloc = [&](size_t bytes) -> void* {
        void* q = (void*)p;
        p += (bytes + 255) / 256 * 256;
        return q;
    };
    int*    bukcnt  = (int*)alloc(256 * 4);
    int*    bb0     = (int*)alloc(257 * 4);
    int*    bbase   = (int*)alloc(256 * 4);
    int*    rowptr  = (int*)alloc((size_t)(N + 1) * 4);
    float*  dinv    = (float*)alloc((size_t)N * 4);
    int*    srcs    = (int*)alloc((size_t)E * 4);
    __half* h       = (__half*)alloc((size_t)N * D * 2);  // aliased as ebuf before GEMMs
    __half* x1      = (__half*)alloc((size_t)N * D * 2);
    unsigned* ebuf  = (unsigned*)h;                        // E*4 <= N*D*2 required

    hipMemsetAsync(bukcnt, 0, 256 * 4, stream);
    k_bukcnt<<<512, 256, 0, stream>>>(col, E, bukcnt);
    k_bukscan<<<1, 256, 0, stream>>>(bukcnt, nbuk, E, bb0, bbase, rowptr, N);

    // CSR build: bucketed binning (coalesced packed runs) then per-bucket LDS work
    k_bin<<<(E + T_TILE - 1) / T_TILE, 256, 0, stream>>>(row, col, E, bbase, ebuf, nbuk);
    k_csr2<<<nbuk, 256, 0, stream>>>(ebuf, bb0, N, rowptr, dinv, srcs);

    // layer 1: hs = fp16((x @ W1) * dinv) ; x1 = fp16(relu(dinv*(hs_self + sum) + b1))
    k_gemm<0><<<(N + 63) / 64, 256, 0, stream>>>(xu, xj, U, N, W1, dinv, h);
    k_agg<<<(N + 3) / 4, 256, 0, stream>>>(h, dinv, rowptr, srcs, b1, x1, N, 1);

    // layer 2: hs2 = fp16((x1 @ W2) * dinv) ; aggregate only at selected nodes, fused w/ predictor
    k_gemm<1><<<(N + 63) / 64, 256, 0, stream>>>(x1, x1, U, N, W2, dinv, h);
    k_initout<<<(B + 255) / 256, 256, 0, stream>>>(pb, out, B);
    k_pred<<<(2 * B + 3) / 4, 256, 0, stream>>>(h, dinv, rowptr, srcs, b2, pw, uidx, jidx, U, B, out);
}

// Round 7
// 351.941 us; speedup vs baseline: 2.3235x; 1.0418x over previous
//
#include <hip/hip_runtime.h>
#include <hip/hip_fp16.h>

#define D 64
#define BSHIFT 10              // nodes per bucket = 1024
#define BMASK ((1 << BSHIFT) - 1)
#define NBUK_MAX 256
#define T_TILE 6144            // edges per k_bin block (256 threads x 24)

#if defined(__has_builtin)
#if __has_builtin(__builtin_amdgcn_fdot2)
#define HAVE_FDOT2 1
#endif
#endif

typedef _Float16 h2f __attribute__((ext_vector_type(2)));

// inclusive wave scan (64 lanes)
__device__ __forceinline__ int wave_iscan(int v, int lane) {
#pragma unroll
    for (int off = 1; off < 64; off <<= 1) {
        int u = __shfl_up(v, off, 64);
        if (lane >= off) v += u;
    }
    return v;
}

// block-wide (256 thr) exclusive scan; returns exclusive prefix
__device__ __forceinline__ int block_escan(int v, int tid, int* wtot /*>=4 ints LDS*/) {
    int lane = tid & 63, w = tid >> 6;
    int inc = wave_iscan(v, lane);
    if (lane == 63) wtot[w] = inc;
    __syncthreads();
    int addv = 0;
#pragma unroll
    for (int q = 0; q < 4; q++) addv += (q < w) ? wtot[q] : 0;
    return inc - v + addv;
}

__device__ __forceinline__ float4 h4_to_f4(uint2 u) {
    __half2 a = *(__half2*)&u.x, b = *(__half2*)&u.y;
    float2 fa = __half22float2(a), fb = __half22float2(b);
    return make_float4(fa.x, fa.y, fb.x, fb.y);
}

// acc += fp16x4(u)  — one VALU op per feature via v_dot2_f32_f16 when available
__device__ __forceinline__ void acc_h4(float4& acc, uint2 u) {
#ifdef HAVE_FDOT2
    h2f a, b;
    __builtin_memcpy(&a, &u.x, 4);
    __builtin_memcpy(&b, &u.y, 4);
    const h2f LO = {(_Float16)1.0f, (_Float16)0.0f};
    const h2f HI = {(_Float16)0.0f, (_Float16)1.0f};
    acc.x = __builtin_amdgcn_fdot2(a, LO, acc.x, false);
    acc.y = __builtin_amdgcn_fdot2(a, HI, acc.y, false);
    acc.z = __builtin_amdgcn_fdot2(b, LO, acc.z, false);
    acc.w = __builtin_amdgcn_fdot2(b, HI, acc.w, false);
#else
    float4 v = h4_to_f4(u);
    acc.x += v.x; acc.y += v.y; acc.z += v.z; acc.w += v.w;
#endif
}

// ---------------- per-bucket edge counts (LDS-privatized) ----------------

__global__ __launch_bounds__(256) void k_bukcnt(const int* __restrict__ col, int E,
                                                int* __restrict__ bukcnt) {
    __shared__ int h[NBUK_MAX];
    h[threadIdx.x] = 0;
    __syncthreads();
    int stride = gridDim.x * 256 * 4;
    for (int base = (blockIdx.x * 256 + threadIdx.x) * 4; base < E; base += stride) {
        if (base + 3 < E) {
            int4 c = *(const int4*)(col + base);
            atomicAdd(&h[c.x >> BSHIFT], 1);
            atomicAdd(&h[c.y >> BSHIFT], 1);
            atomicAdd(&h[c.z >> BSHIFT], 1);
            atomicAdd(&h[c.w >> BSHIFT], 1);
        } else {
            for (int k = base; k < E; k++) atomicAdd(&h[col[k] >> BSHIFT], 1);
        }
    }
    __syncthreads();
    int v = h[threadIdx.x];
    if (v) atomicAdd(&bukcnt[threadIdx.x], v);
}

// ---------------- bucket base scan (single block) + zero sentinel row ----------------

__global__ void k_bukscan(const int* __restrict__ bukcnt, int nbuk, int E,
                          int* __restrict__ bb0, int* __restrict__ bbase,
                          int* __restrict__ rowptr, int N, __half* __restrict__ h) {
    __shared__ int wtot[4];
    int tid = threadIdx.x;
    int v = (tid < nbuk) ? bukcnt[tid] : 0;
    int excl = block_escan(v, tid, wtot);
    if (tid < nbuk) { bb0[tid] = excl; bbase[tid] = excl; }
    if (tid == 0) { bb0[nbuk] = E; rowptr[N] = E; }
    if (tid < 16) {  // zero sentinel row N (beyond ebuf alias region)
        uint2 z; z.x = 0u; z.y = 0u;
        *(uint2*)(h + (size_t)N * D + tid * 4) = z;
    }
}

// ---------------- bucket binning with LDS reorder (per-wave hist/cursors) ----------------
// packed entry: (c & BMASK) << 18 | r   — requires N <= 2^18 (N=200000 here)

__global__ __launch_bounds__(256) void k_bin(const int* __restrict__ row, const int* __restrict__ col,
                                             int E, int* __restrict__ bbase,
                                             unsigned* __restrict__ ebuf, int nbuk) {
    __shared__ int hist4[4][NBUK_MAX];     // 4 KB
    __shared__ int sexcl[NBUK_MAX];
    __shared__ int cur4[4][NBUK_MAX];      // 4 KB
    __shared__ int gbase[NBUK_MAX];
    __shared__ int wtot[4];
    __shared__ unsigned stage[T_TILE];     // 24 KB
    __shared__ unsigned char sbuk[T_TILE]; // 6 KB
    int tid = threadIdx.x;
    int w = tid >> 6;
    int tile0 = blockIdx.x * T_TILE;
    int cnt = min(T_TILE, E - tile0);

#pragma unroll
    for (int q = 0; q < 4; q++) hist4[q][tid] = 0;
    __syncthreads();
    for (int i = tid; i < cnt; i += 256)
        atomicAdd(&hist4[w][col[tile0 + i] >> BSHIFT], 1);
    __syncthreads();

    int h0 = hist4[0][tid], h1 = hist4[1][tid], h2 = hist4[2][tid], h3 = hist4[3][tid];
    int v = h0 + h1 + h2 + h3;
    int excl = block_escan(v, tid, wtot);
    sexcl[tid] = excl;
    cur4[0][tid] = excl;
    cur4[1][tid] = excl + h0;
    cur4[2][tid] = excl + h0 + h1;
    cur4[3][tid] = excl + h0 + h1 + h2;
    gbase[tid] = (v > 0 && tid < nbuk) ? atomicAdd(&bbase[tid], v) : 0;
    __syncthreads();

    for (int i = tid; i < cnt; i += 256) {
        int r = row[tile0 + i];
        int c = col[tile0 + i];
        int b = c >> BSHIFT;
        int p = atomicAdd(&cur4[w][b], 1);
        stage[p] = ((unsigned)(c & BMASK) << 18) | (unsigned)r;
        sbuk[p] = (unsigned char)b;
    }
    __syncthreads();

    for (int i = tid; i < cnt; i += 256) {
        int b = sbuk[i];
        int gpos = gbase[b] + (i - sexcl[b]);
        ebuf[gpos] = stage[i];
    }
}

// ---------------- per-bucket degree count + rowptr + dinv + CSR scatter ----------------

__global__ __launch_bounds__(256) void k_csr2(const unsigned* __restrict__ ebuf,
                                              const int* __restrict__ bb0, int N,
                                              int* __restrict__ rowptr, float* __restrict__ dinv,
                                              int* __restrict__ srcs) {
    __shared__ int lcnt[1 << BSHIFT];  // 4 KB
    __shared__ int lcur[1 << BSHIFT];  // 4 KB
    __shared__ int wtot[4];
    int tid = threadIdx.x;
    int c0 = blockIdx.x << BSHIFT;
    int nn = min(1 << BSHIFT, N - c0);
    int e0 = bb0[blockIdx.x], e1 = bb0[blockIdx.x + 1];

    for (int i = tid; i < (1 << BSHIFT); i += 256) lcnt[i] = 0;
    __syncthreads();
    for (int j = e0 + tid; j < e1; j += 256)
        atomicAdd(&lcnt[ebuf[j] >> 18], 1);
    __syncthreads();

    int c[4]; int s = 0;
#pragma unroll
    for (int i = 0; i < 4; i++) { c[i] = lcnt[tid * 4 + i]; s += c[i]; }
    int run = block_escan(s, tid, wtot);
    __syncthreads();
#pragma unroll
    for (int i = 0; i < 4; i++) {
        int idx = tid * 4 + i;
        lcur[idx] = run;
        if (idx < nn) {
            rowptr[c0 + idx] = e0 + run;
            dinv[c0 + idx] = rsqrtf((float)(c[i] + 1));  // +1 self loop
        }
        run += c[i];
    }
    __syncthreads();

    for (int j = e0 + tid; j < e1; j += 256) {
        unsigned pk = ebuf[j];
        int p = atomicAdd(&lcur[pk >> 18], 1);
        srcs[e0 + p] = (int)(pk & 0x3ffffu);
    }
}

// ---------------- dense: h[n][c] = fp16( dinv[n] * sum_k x[n][k] * W[k][c] ) ----------------

template<int IN_HALF>
__global__ __launch_bounds__(256) void k_gemm(const void* __restrict__ xu_, const void* __restrict__ xj_,
                                              int U, int N, const float* __restrict__ W,
                                              const float* __restrict__ dinv, __half* __restrict__ h) {
    __shared__ float Ws[64 * 64];
    __shared__ float Xs[64 * 68];
    int tid = threadIdx.x;
#pragma unroll
    for (int i = 0; i < 16; i++) Ws[tid + i * 256] = W[tid + i * 256];
    int n0 = blockIdx.x * 64;
#pragma unroll
    for (int i = 0; i < 4; i++) {
        int e4 = tid + i * 256;
        int nl = e4 >> 4, k4 = e4 & 15;
        int nn = n0 + nl;
        float4 v = make_float4(0.f, 0.f, 0.f, 0.f);
        if (nn < N) {
            if (IN_HALF) {
                const __half* src = (const __half*)xu_ + (size_t)nn * D;
                v = h4_to_f4(*(const uint2*)(src + k4 * 4));
            } else {
                const float* src = (nn < U) ? ((const float*)xu_ + (size_t)nn * D)
                                            : ((const float*)xj_ + (size_t)(nn - U) * D);
                v = *(const float4*)(src + k4 * 4);
            }
        }
        *(float4*)(&Xs[nl * 68 + k4 * 4]) = v;
    }
    __syncthreads();
    int tx = tid & 15, ty = tid >> 4;
    float acc[4][4];
#pragma unroll
    for (int r = 0; r < 4; r++)
#pragma unroll
        for (int c = 0; c < 4; c++) acc[r][c] = 0.f;
#pragma unroll 16
    for (int k = 0; k < 64; k++) {
        float xv[4], wv[4];
#pragma unroll
        for (int r = 0; r < 4; r++) xv[r] = Xs[(ty * 4 + r) * 68 + k];
#pragma unroll
        for (int c = 0; c < 4; c++) wv[c] = Ws[k * 64 + tx * 4 + c];
#pragma unroll
        for (int r = 0; r < 4; r++)
#pragma unroll
            for (int c = 0; c < 4; c++) acc[r][c] += xv[r] * wv[c];
    }
#pragma unroll
    for (int r = 0; r < 4; r++) {
        int nn = n0 + ty * 4 + r;
        if (nn < N) {
            float sc = dinv[nn];
            __half2 p0 = __floats2half2_rn(acc[r][0] * sc, acc[r][1] * sc);
            __half2 p1 = __floats2half2_rn(acc[r][2] * sc, acc[r][3] * sc);
            uint2 st; st.x = *(unsigned*)&p0; st.y = *(unsigned*)&p1;
            *(uint2*)(h + (size_t)nn * D + tx * 4) = st;
        }
    }
}

// ---------------- neighborhood accumulate helper (shared by k_agg / k_pred) ----------------
// wave = 1 node; lane = g*16+t; group g handles slots {ii+g, ii+4+g, ii+8+g, ii+12+g};
// OOB slots read zeroed sentinel row N -> unconditional fdot2 accumulate.

__device__ __forceinline__ float4 gather_node(const __half* __restrict__ hs,
                                              const int* __restrict__ rowptr,
                                              const int* __restrict__ srcs,
                                              int node, int N, int lane, int g, int t) {
    const __half* hp = hs + t * 4;
    float4 acc = make_float4(0.f, 0.f, 0.f, 0.f);
    int e0 = rowptr[node], e1 = rowptr[node + 1];
    for (int base0 = e0; base0 < e1; base0 += 64) {
        int j = base0 + lane;
        int s = (j < e1) ? srcs[j] : 0;
        int cnt = min(64, e1 - base0);
        for (int ii = 0; ii < cnt; ii += 16) {
            int i0 = ii + g, i1 = ii + g + 4, i2 = ii + g + 8, i3 = ii + g + 12;
            int s0 = __shfl(s, i0, 64); s0 = (i0 < cnt) ? s0 : N;
            int s1 = __shfl(s, i1, 64); s1 = (i1 < cnt) ? s1 : N;
            int s2 = __shfl(s, i2, 64); s2 = (i2 < cnt) ? s2 : N;
            int s3 = __shfl(s, i3, 64); s3 = (i3 < cnt) ? s3 : N;
            uint2 u0 = *(const uint2*)(hp + (size_t)s0 * D);
            uint2 u1 = *(const uint2*)(hp + (size_t)s1 * D);
            uint2 u2 = *(const uint2*)(hp + (size_t)s2 * D);
            uint2 u3 = *(const uint2*)(hp + (size_t)s3 * D);
            acc_h4(acc, u0);
            acc_h4(acc, u1);
            acc_h4(acc, u2);
            acc_h4(acc, u3);
        }
    }
    // cross-group reduction -> full sums replicated in every group
    acc.x += __shfl_xor(acc.x, 16, 64); acc.x += __shfl_xor(acc.x, 32, 64);
    acc.y += __shfl_xor(acc.y, 16, 64); acc.y += __shfl_xor(acc.y, 32, 64);
    acc.z += __shfl_xor(acc.z, 16, 64); acc.z += __shfl_xor(acc.z, 32, 64);
    acc.w += __shfl_xor(acc.w, 16, 64); acc.w += __shfl_xor(acc.w, 32, 64);
    return acc;
}

// ---------------- pull aggregation (full N) ----------------

__global__ __launch_bounds__(256) void k_agg(const __half* __restrict__ hs, const float* __restrict__ dinv,
                                             const int* __restrict__ rowptr, const int* __restrict__ srcs,
                                             const float* __restrict__ bias, __half* __restrict__ xout,
                                             int N, int do_relu) {
    int node = blockIdx.x * 4 + (threadIdx.x >> 6);
    int lane = threadIdx.x & 63;
    int g = lane >> 4, t = lane & 15;
    if (node >= N) return;
    float4 acc = gather_node(hs, rowptr, srcs, node, N, lane, g, t);
    float4 self = h4_to_f4(*(const uint2*)(hs + (size_t)node * D + t * 4));
    float4 b4 = *(const float4*)(bias + t * 4);
    float dv = dinv[node];
    float4 o;
    o.x = (acc.x + self.x) * dv + b4.x;
    o.y = (acc.y + self.y) * dv + b4.y;
    o.z = (acc.z + self.z) * dv + b4.z;
    o.w = (acc.w + self.w) * dv + b4.w;
    if (do_relu) {
        o.x = fmaxf(o.x, 0.f); o.y = fmaxf(o.y, 0.f);
        o.z = fmaxf(o.z, 0.f); o.w = fmaxf(o.w, 0.f);
    }
    if (g == 0) {
        __half2 p0 = __floats2half2_rn(o.x, o.y);
        __half2 p1 = __floats2half2_rn(o.z, o.w);
        uint2 st; st.x = *(unsigned*)&p0; st.y = *(unsigned*)&p1;
        *(uint2*)(xout + (size_t)node * D + t * 4) = st;
    }
}

// ---------------- fused layer-2 both-sides aggregation + prediction (direct store) ----------------

__global__ __launch_bounds__(256) void k_pred(const __half* __restrict__ hs2, const float* __restrict__ dinv,
                                              const int* __restrict__ rowptr, const int* __restrict__ srcs,
                                              const float* __restrict__ b2, const float* __restrict__ pw,
                                              const float* __restrict__ pb,
                                              const int* __restrict__ uidx, const int* __restrict__ jidx,
                                              int U, int N, int B, float* __restrict__ out) {
    int b = blockIdx.x * 4 + (threadIdx.x >> 6);
    int lane = threadIdx.x & 63;
    int g = lane >> 4, t = lane & 15;
    if (b >= B) return;
    float4 b4 = *(const float4*)(b2 + t * 4);
    float vx = 0.f;
#pragma unroll
    for (int side = 0; side < 2; side++) {
        int c = (side == 0) ? uidx[b] : U + jidx[b];
        float4 acc = gather_node(hs2, rowptr, srcs, c, N, lane, g, t);
        float4 self = h4_to_f4(*(const uint2*)(hs2 + (size_t)c * D + t * 4));
        float dv = dinv[c];
        float4 w4 = *(const float4*)(pw + side * 64 + t * 4);
        vx += ((acc.x + self.x) * dv + b4.x) * w4.x
            + ((acc.y + self.y) * dv + b4.y) * w4.y
            + ((acc.z + self.z) * dv + b4.z) * w4.z
            + ((acc.w + self.w) * dv + b4.w) * w4.w;
    }
    vx += __shfl_xor(vx, 1, 64); vx += __shfl_xor(vx, 2, 64);
    vx += __shfl_xor(vx, 4, 64); vx += __shfl_xor(vx, 8, 64);
    if (lane == 0) out[b] = vx + pb[0];
}

// ---------------- host ----------------

extern "C" void kernel_launch(void* const* d_in, const int* in_sizes, int n_in,
                              void* d_out, int out_size, void* d_ws, size_t ws_size,
                              hipStream_t stream) {
    const int*   edge = (const int*)d_in[0];
    const int*   uidx = (const int*)d_in[1];
    const int*   jidx = (const int*)d_in[2];
    const float* xu   = (const float*)d_in[3];
    const float* xj   = (const float*)d_in[4];
    const float* W1   = (const float*)d_in[5];
    const float* b1   = (const float*)d_in[6];
    const float* W2   = (const float*)d_in[7];
    const float* b2   = (const float*)d_in[8];
    const float* pw   = (const float*)d_in[9];
    const float* pb   = (const float*)d_in[10];
    float* out = (float*)d_out;

    int E = in_sizes[0] / 2;
    int B = in_sizes[1];
    int U = in_sizes[3] / D;
    int J = in_sizes[4] / D;
    int N = U + J;
    int nbuk = (N + (1 << BSHIFT) - 1) >> BSHIFT;   // 196 for N=200000; must be <= 256
    const int* row = edge;       // sources
    const int* col = edge + E;   // targets

    char* p = (char*)d_ws;
    auto alloc = [&](size_t bytes) -> void* {
        void* q = (void*)p;
        p += (bytes + 255) / 256 * 256;
        return q;
    };
    int*    bukcnt  = (int*)alloc(256 * 4);
    int*    bb0     = (int*)alloc(257 * 4);
    int*    bbase   = (int*)alloc(256 * 4);
    int*    rowptr  = (int*)alloc((size_t)(N + 1) * 4);
    float*  dinv    = (float*)alloc((size_t)N * 4);
    int*    srcs    = (int*)alloc((size_t)E * 4);
    __half* h       = (__half*)alloc((size_t)(N + 1) * D * 2);  // +1 sentinel row; aliased as ebuf early
    __half* x1      = (__half*)alloc((size_t)N * D * 2);
    unsigned* ebuf  = (unsigned*)h;                        // E*4 <= N*D*2 required

    hipMemsetAsync(bukcnt, 0, 256 * 4, stream);
    k_bukcnt<<<512, 256, 0, stream>>>(col, E, bukcnt);
    k_bukscan<<<1, 256, 0, stream>>>(bukcnt, nbuk, E, bb0, bbase, rowptr, N, h);

    // CSR build: bucketed binning (coalesced packed runs) then per-bucket LDS work
    k_bin<<<(E + T_TILE - 1) / T_TILE, 256, 0, stream>>>(row, col, E, bbase, ebuf, nbuk);
    k_csr2<<<nbuk, 256, 0, stream>>>(ebuf, bb0, N, rowptr, dinv, srcs);

    // layer 1: hs = fp16((x @ W1) * dinv) ; x1 = fp16(relu(dinv*(hs_self + sum) + b1))
    k_gemm<0><<<(N + 63) / 64, 256, 0, stream>>>(xu, xj, U, N, W1, dinv, h);
    k_agg<<<(N + 3) / 4, 256, 0, stream>>>(h, dinv, rowptr, srcs, b1, x1, N, 1);

    // layer 2: hs2 = fp16((x1 @ W2) * dinv) ; both-sides aggregation fused w/ predictor
    k_gemm<1><<<(N + 63) / 64, 256, 0, stream>>>(x1, x1, U, N, W2, dinv, h);
    k_pred<<<(B + 3) / 4, 256, 0, stream>>>(h, dinv, rowptr, srcs, b2, pw, pb, uidx, jidx, U, N, B, out);
}